// Round 6
// baseline (370.985 us; speedup 1.0000x reference)
//
#include <hip/hip_runtime.h>
#include <hip/hip_bf16.h>

#define HW   4096

typedef __bf16 bf_t;
typedef __bf16 bf8_t __attribute__((ext_vector_type(8)));
typedef float  f4_t  __attribute__((ext_vector_type(4)));

// Static device workspace (element offsets into g_ws, in floats):
#define OFF_A  0              // 2*50*HW   = 409600 (18ch then 50ch offsets)
#define OFF_B  409600         // 2*98*HW   = 802816
#define WS_A1  1212416        // 2*64*HW   = 524288 each
#define WS_A2  1736704
#define WS_B1  2260992
#define WS_B2  2785280
#define XA_HI  3309568        // bf16[2*64*HW] = 262144 floats each
#define XA_LO  3571712
#define XB_HI  3833856
#define XB_LO  4096000
#define A1_HI  4358144
#define A1_LO  4620288
#define B1_HI  4882432
#define B1_LO  5144576
#define AW_A1  5406720        // k3:  9*2*128*8  bf16 -> 9216 fl
#define AW_B1  5415936        // k5: 25*4*128*8  bf16 -> 51200 fl
#define AW_A2  5467136        // k5: same
#define AW_B2  5518336        // k7: 49*8*128*8  bf16 -> 200704 fl
#define WS_TOT 5719040

__device__ float g_ws[WS_TOT];

__device__ __forceinline__ bf8_t bf8_zero() {
    bf8_t v;
#pragma unroll
    for (int j = 0; j < 8; ++j) v[j] = (bf_t)0.f;
    return v;
}

// ---------------------------------------------------------------------------
// fp32 NCHW (64ch, batch stride bstride) -> two bf16 NHWC buffers (hi, lo):
// a = hi + lo, hi = bf16(a), lo = bf16(a - hi).
// grid (B, 256): 16-px tiles -> 512 blocks.
// ---------------------------------------------------------------------------
__global__ __launch_bounds__(256) void split_nhwc_kernel(
    const float* __restrict__ src_ext, int src_off, int bstride,
    int hi_off, int lo_off)
{
    const float* src = src_ext ? src_ext : (const float*)(g_ws + src_off);
    bf_t* dhi = (bf_t*)(g_ws + hi_off);
    bf_t* dlo = (bf_t*)(g_ws + lo_off);
    __shared__ float lds[16 * 68];
    const int b  = blockIdx.x;
    const int p0 = blockIdx.y * 16;
    const int t  = threadIdx.x;
    const float* sb = src + (long)b * bstride;
    {
        const int px = t & 15;
        const int c0 = t >> 4;      // 16 ci per pass
#pragma unroll
        for (int pass = 0; pass < 4; ++pass) {
            int ci = c0 + pass * 16;
            lds[px * 68 + ci] = sb[ci * HW + p0 + px];
        }
    }
    __syncthreads();
    if (t < 128) {
        int px = t >> 3, q = t & 7;
        bf8_t vh, vl;
#pragma unroll
        for (int j = 0; j < 8; ++j) {
            float a = lds[px * 68 + q * 8 + j];
            bf_t hcast = (bf_t)a;
            vh[j] = hcast;
            vl[j] = (bf_t)(a - (float)hcast);
        }
        long base = (((long)b * 4096 + p0 + px) * 64) + q * 8;
        *(bf8_t*)&dhi[base] = vh;
        *(bf8_t*)&dlo[base] = vl;
    }
}

// ---------------------------------------------------------------------------
// Weight pack: wg fp32 [Cout][64][K][K] -> bf16 A-fragment layout:
// aw[((tap*NCOT + cot)*2 + kh)*64 + lane][8] ; m=co=cot*16+(lane&15),
// k=ci=kh*32+(lane>>4)*8+j. Zero-padded beyond Cout.
// ---------------------------------------------------------------------------
template<int K, int NCOT>
__global__ __launch_bounds__(256) void prep_wA_kernel(const float* __restrict__ wg,
                                                      int aw_off, int Cout) {
    bf_t* aw = (bf_t*)(g_ws + aw_off);
    constexpr int KK = K * K;
    const int total = KK * NCOT * 2 * 64;
    for (int idx = blockIdx.x * 256 + threadIdx.x; idx < total; idx += gridDim.x * 256) {
        int lane = idx & 63;
        int kh   = (idx >> 6) & 1;
        int cot  = (idx >> 7) % NCOT;
        int tap  = idx / (128 * NCOT);
        int co   = cot * 16 + (lane & 15);
        int ci0  = kh * 32 + (lane >> 4) * 8;
        bf8_t v;
#pragma unroll
        for (int j = 0; j < 8; ++j) {
            float f = (co < Cout) ? wg[(co * 64 + ci0 + j) * KK + tap] : 0.f;
            v[j] = (bf_t)f;
        }
        *(bf8_t*)&aw[(long)idx * 8] = v;
    }
}

// ---------------------------------------------------------------------------
// MFMA implicit-GEMM conv with hi/lo split input for ~fp32 accuracy.
// grid (B*64 rows, 2); block 256 (4 waves = 4 pixel-tiles of 16).
// Each wave accumulates CPG co-tiles of 16.
// ---------------------------------------------------------------------------
template<int K, int DIL, int PAD, int NCOT, int CPG>
__global__ __launch_bounds__(256) void mfma_conv_kernel(
    int hi_off, int lo_off, int aw_off, const float* __restrict__ bias,
    int dst_off, int Cout)
{
    constexpr int COLS = 64 + 2 * PAD;
    const bf_t* shi = (const bf_t*)(g_ws + hi_off);
    const bf_t* slo = (const bf_t*)(g_ws + lo_off);
    const bf_t* aw  = (const bf_t*)(g_ws + aw_off);
    float* dst = g_ws + dst_off;
    __shared__ __align__(16) bf_t lds[2][COLS * 72];

    const int t    = threadIdx.x;
    const int lane = t & 63;
    const int wv   = t >> 6;            // pixel tile
    const int b    = blockIdx.x >> 6;
    const int h    = blockIdx.x & 63;
    const int ct0  = blockIdx.y * CPG;

    const int n0 = lane & 15;           // pixel within tile
    const int kq = lane >> 4;           // quad id

    f4_t acc[CPG];
#pragma unroll
    for (int i = 0; i < CPG; ++i) acc[i] = (f4_t){0.f, 0.f, 0.f, 0.f};

    for (int ky = 0; ky < K; ++ky) {
        const int ih = h - PAD + ky * DIL;
        __syncthreads();
        if ((unsigned)ih < 64u) {
            const long rowb = ((long)b * 4096 + ih * 64) * 64;
            for (int c = t; c < COLS * 8; c += 256) {
                int col = c >> 3, q = c & 7;
                int iw = col - PAD;
                bf8_t vh, vl;
                if ((unsigned)iw < 64u) {
                    vh = *(const bf8_t*)&shi[rowb + iw * 64 + q * 8];
                    vl = *(const bf8_t*)&slo[rowb + iw * 64 + q * 8];
                } else { vh = bf8_zero(); vl = bf8_zero(); }
                *(bf8_t*)&lds[0][col * 72 + q * 8] = vh;
                *(bf8_t*)&lds[1][col * 72 + q * 8] = vl;
            }
        } else {
            bf8_t z = bf8_zero();
            for (int c = t; c < COLS * 8; c += 256) {
                int col = c >> 3, q = c & 7;
                *(bf8_t*)&lds[0][col * 72 + q * 8] = z;
                *(bf8_t*)&lds[1][col * 72 + q * 8] = z;
            }
        }
        __syncthreads();
#pragma unroll
        for (int kx = 0; kx < K; ++kx) {
            const int tap = ky * K + kx;
            bf8_t afr[CPG][2];
#pragma unroll
            for (int ct = 0; ct < CPG; ++ct)
#pragma unroll
                for (int kh = 0; kh < 2; ++kh)
                    afr[ct][kh] = *(const bf8_t*)
                        &aw[((((long)tap * NCOT + ct0 + ct) * 2 + kh) * 64 + lane) * 8];
            const int colb = (wv * 16 + n0 + kx * DIL) * 72;
#pragma unroll
            for (int kh = 0; kh < 2; ++kh) {
                const bf8_t bh = *(const bf8_t*)&lds[0][colb + kh * 32 + kq * 8];
                const bf8_t bl = *(const bf8_t*)&lds[1][colb + kh * 32 + kq * 8];
#pragma unroll
                for (int ct = 0; ct < CPG; ++ct) {
                    acc[ct] = __builtin_amdgcn_mfma_f32_16x16x32_bf16(
                        afr[ct][kh], bh, acc[ct], 0, 0, 0);
                    acc[ct] = __builtin_amdgcn_mfma_f32_16x16x32_bf16(
                        afr[ct][kh], bl, acc[ct], 0, 0, 0);
                }
            }
        }
    }

    const int w = wv * 16 + n0;
#pragma unroll
    for (int ct = 0; ct < CPG; ++ct) {
#pragma unroll
        for (int r = 0; r < 4; ++r) {
            int co = (ct0 + ct) * 16 + kq * 4 + r;
            if (co < Cout)
                dst[((long)b * Cout + co) * HW + h * 64 + w] = acc[ct][r] + bias[co];
        }
    }
}

// ---------------------------------------------------------------------------
// Depthwise deformable sampling (fp32). One channel per thread.
// grid (B*H = 128, 16); block 256 = 4 waves x 64 w-lanes; wave -> channel
// c = blockIdx.y*4 + wave. Per-output arithmetic identical to prior rounds.
// ---------------------------------------------------------------------------
template<int K>
__global__ __launch_bounds__(256) void deform_kernel(
    const float* __restrict__ src_ext, int src_off, int bstride,
    int off_off, const float* __restrict__ wdw,
    int dst_off, int pad, int dil)
{
    constexpr int KK = K * K;
    const float* src = src_ext ? src_ext : (const float*)(g_ws + src_off);
    const float* off = g_ws + off_off;
    float*       dst = g_ws + dst_off;

    const int tid = threadIdx.x;
    const int w   = tid & 63;
    const int b   = blockIdx.x >> 6;
    const int h   = blockIdx.x & 63;
    const int c   = (int)(blockIdx.y << 2) + (tid >> 6);

    const float* offb = off + (long)b * (2 * KK) * HW + h * 64 + w;
    const float* sc   = src + (long)b * bstride + (long)c * HW;
    const float* wc   = wdw + c * KK;

    float acc = 0.f;

    for (int kk = 0; kk < KK; ++kk) {
        const float oy = offb[(2 * kk) * HW];
        const float ox = offb[(2 * kk + 1) * HW];
        const float py = oy + (float)(h - pad + (kk / K) * dil);
        const float px = ox + (float)(w - pad + (kk % K) * dil);
        const float fy = floorf(py), fx = floorf(px);
        const float ly = py - fy,    lx = px - fx;
        const int y0 = (int)fy, x0 = (int)fx;
        const int y1 = y0 + 1,  x1 = x0 + 1;
        const float vy0 = ((unsigned)y0 < 64u) ? 1.f : 0.f;
        const float vy1 = ((unsigned)y1 < 64u) ? 1.f : 0.f;
        const float vx0 = ((unsigned)x0 < 64u) ? 1.f : 0.f;
        const float vx1 = ((unsigned)x1 < 64u) ? 1.f : 0.f;
        const float w00 = (1.f - ly) * (1.f - lx) * vy0 * vx0;
        const float w01 = (1.f - ly) * lx         * vy0 * vx1;
        const float w10 = ly         * (1.f - lx) * vy1 * vx0;
        const float w11 = ly         * lx         * vy1 * vx1;
        const int y0c = min(max(y0, 0), 63), y1c = min(max(y1, 0), 63);
        const int x0c = min(max(x0, 0), 63), x1c = min(max(x1, 0), 63);
        const int i00 = y0c * 64 + x0c, i01 = y0c * 64 + x1c;
        const int i10 = y1c * 64 + x0c, i11 = y1c * 64 + x1c;
        float val = w00 * sc[i00] + w01 * sc[i01]
                  + w10 * sc[i10] + w11 * sc[i11];
        acc = fmaf(wc[kk], val, acc);
    }

    dst[((long)b * 64 + c) * HW + h * 64 + w] = acc;
}

// ---------------------------------------------------------------------------
// Final: per-branch 1x1 conv (+bias), then out = x * result.  fp32 out.
// ---------------------------------------------------------------------------
__global__ __launch_bounds__(256) void final_kernel(
    const float* __restrict__ x,
    int aA_off, int aB_off,
    const float* __restrict__ w1, const float* __restrict__ b1,
    const float* __restrict__ w2, const float* __restrict__ b2,
    float* __restrict__ out)
{
    __shared__ float wlds[512];
    const int tid = threadIdx.x;
    const int p   = blockIdx.x * 256 + tid;
    const int co0 = blockIdx.y << 3;
    const int b   = blockIdx.z;
    const bool brB = (co0 >= 64);
    const int  cl0 = co0 & 63;
    const float* a  = g_ws + (brB ? aB_off : aA_off);
    const float* wg = brB ? w2 : w1;
    const float* bg = brB ? b2 : b1;

    for (int e = tid; e < 512; e += 256) {
        int ci = e >> 3, j = e & 7;
        wlds[e] = wg[(cl0 + j) * 64 + ci];
    }
    __syncthreads();

    float acc[8] = {0, 0, 0, 0, 0, 0, 0, 0};
    const float* ab = a + (long)b * 64 * HW + p;
    for (int ci = 0; ci < 64; ++ci) {
        const float av = ab[ci * HW];
        const float* wr = &wlds[ci * 8];
#pragma unroll
        for (int j = 0; j < 8; ++j) acc[j] = fmaf(av, wr[j], acc[j]);
    }

    const float* xb = x   + ((long)b * 128 + co0) * HW + p;
    float*       ob = out + ((long)b * 128 + co0) * HW + p;
#pragma unroll
    for (int j = 0; j < 8; ++j) {
        ob[j * HW] = (acc[j] + bg[cl0 + j]) * xb[j * HW];
    }
}

// ---------------------------------------------------------------------------
extern "C" void kernel_launch(void* const* d_in, const int* in_sizes, int n_in,
                              void* d_out, int out_size, void* d_ws, size_t ws_size,
                              hipStream_t stream) {
    const float* x         = (const float*)d_in[0];
    const float* cv0_off_w = (const float*)d_in[1];
    const float* cv0_off_b = (const float*)d_in[2];
    const float* cv0_w     = (const float*)d_in[3];
    const float* cvs_off_w = (const float*)d_in[4];
    const float* cvs_off_b = (const float*)d_in[5];
    const float* cvs_w     = (const float*)d_in[6];
    const float* c0_off_w  = (const float*)d_in[7];
    const float* c0_off_b  = (const float*)d_in[8];
    const float* c0_w      = (const float*)d_in[9];
    const float* cs_off_w  = (const float*)d_in[10];
    const float* cs_off_b  = (const float*)d_in[11];
    const float* cs_w      = (const float*)d_in[12];
    const float* conv1_w   = (const float*)d_in[13];
    const float* conv1_b   = (const float*)d_in[14];
    const float* conv2_w   = (const float*)d_in[15];
    const float* conv2_b   = (const float*)d_in[16];
    float* out = (float*)d_out;
    (void)d_ws; (void)ws_size;

    const int XB = 128 * HW;
    const int AB = 64 * HW;

    // weight packs (tiny)
    prep_wA_kernel<3, 2><<<dim3(9),   256, 0, stream>>>(cv0_off_w, AW_A1, 18);
    prep_wA_kernel<5, 4><<<dim3(50),  256, 0, stream>>>(c0_off_w,  AW_B1, 50);
    prep_wA_kernel<5, 4><<<dim3(50),  256, 0, stream>>>(cvs_off_w, AW_A2, 50);
    prep_wA_kernel<7, 8><<<dim3(196), 256, 0, stream>>>(cs_off_w,  AW_B2, 98);

    // hi/lo bf16 NHWC splits of x branches
    split_nhwc_kernel<<<dim3(2, 256), 256, 0, stream>>>(x,           0, XB, XA_HI, XA_LO);
    split_nhwc_kernel<<<dim3(2, 256), 256, 0, stream>>>(x + 64 * HW, 0, XB, XB_HI, XB_LO);

    // stage 1: offset convs (MFMA, split input)
    mfma_conv_kernel<3, 1, 1, 2, 1><<<dim3(128, 2), 256, 0, stream>>>(
        XA_HI, XA_LO, AW_A1, cv0_off_b, OFF_A, 18);
    mfma_conv_kernel<5, 1, 2, 4, 2><<<dim3(128, 2), 256, 0, stream>>>(
        XB_HI, XB_LO, AW_B1, c0_off_b, OFF_B, 50);

    // stage 1: deformable depthwise
    deform_kernel<3><<<dim3(128, 16), 256, 0, stream>>>(
        x, 0, XB, OFF_A, cv0_w, WS_A1, 1, 1);
    deform_kernel<5><<<dim3(128, 16), 256, 0, stream>>>(
        x + 64 * HW, 0, XB, OFF_B, c0_w, WS_B1, 2, 1);

    // hi/lo splits of stage-1 activations
    split_nhwc_kernel<<<dim3(2, 256), 256, 0, stream>>>(nullptr, WS_A1, AB, A1_HI, A1_LO);
    split_nhwc_kernel<<<dim3(2, 256), 256, 0, stream>>>(nullptr, WS_B1, AB, B1_HI, B1_LO);

    // stage 2: offset convs (MFMA, split input)
    mfma_conv_kernel<5, 3, 6, 4, 2><<<dim3(128, 2), 256, 0, stream>>>(
        A1_HI, A1_LO, AW_A2, cvs_off_b, OFF_A, 50);
    mfma_conv_kernel<7, 3, 9, 8, 4><<<dim3(128, 2), 256, 0, stream>>>(
        B1_HI, B1_LO, AW_B2, cs_off_b, OFF_B, 98);

    // stage 2: deformable depthwise
    deform_kernel<5><<<dim3(128, 16), 256, 0, stream>>>(
        nullptr, WS_A1, AB, OFF_A, cvs_w, WS_A2, 6, 3);
    deform_kernel<7><<<dim3(128, 16), 256, 0, stream>>>(
        nullptr, WS_B1, AB, OFF_B, cs_w, WS_B2, 9, 3);

    // 1x1 convs + gating multiply
    final_kernel<<<dim3(16, 16, 2), 256, 0, stream>>>(
        x, WS_A2, WS_B2, conv1_w, conv1_b, conv2_w, conv2_b, out);
}

// Round 7
// 291.993 us; speedup vs baseline: 1.2705x; 1.2705x over previous
//
#include <hip/hip_runtime.h>
#include <hip/hip_bf16.h>

#define HW   4096

typedef __bf16 bf_t;
typedef __bf16 bf8_t __attribute__((ext_vector_type(8)));
typedef float  f4_t  __attribute__((ext_vector_type(4)));

// Static device workspace (element offsets into g_ws, in floats):
#define OFF_A   0              // 2*50*HW  = 409600 (18ch then 50ch offsets, NCHW)
#define OFF_B   409600         // 2*98*HW  = 802816
#define A1_F32  1212416        // NHWC fp32 [b][4096][64] = 524288 each
#define B1_F32  1736704
#define A2_F32  2260992
#define B2_F32  2785280
#define XA_F32  3309568
#define XB_F32  3833856
#define XA_HI   4358144        // bf16 NHWC = 262144 floats each
#define XA_LO   4620288
#define XB_HI   4882432
#define XB_LO   5144576
#define A1_HI   5406720
#define A1_LO   5668864
#define B1_HI   5931008
#define B1_LO   6193152
#define AW_A1   6455296        // conv weight packs (bf16 A-frag)
#define AW_B1   6464512
#define AW_A2   6515712
#define AW_B2   6566912
#define DW_A1   6767616        // depthwise weights transposed [KK][64]
#define DW_B1   6768192
#define DW_A2   6769792
#define DW_B2   6771392
#define WS_TOT  6774528

__device__ float g_ws[WS_TOT];

__device__ __forceinline__ bf8_t bf8_zero() {
    bf8_t v;
#pragma unroll
    for (int j = 0; j < 8; ++j) v[j] = (bf_t)0.f;
    return v;
}

// ---------------------------------------------------------------------------
// x NCHW (64ch branch) -> bf16 NHWC hi/lo + fp32 NHWC. grid (B, 256), blk 256.
// ---------------------------------------------------------------------------
__global__ __launch_bounds__(256) void split_x_kernel(
    const float* __restrict__ src, int bstride,
    int hi_off, int lo_off, int f32_off)
{
    bf_t*  dhi = (bf_t*)(g_ws + hi_off);
    bf_t*  dlo = (bf_t*)(g_ws + lo_off);
    float* df  = g_ws + f32_off;
    __shared__ float lds[16 * 68];
    const int b  = blockIdx.x;
    const int p0 = blockIdx.y * 16;
    const int t  = threadIdx.x;
    const float* sb = src + (long)b * bstride;
    {
        const int px = t & 15;
        const int c0 = t >> 4;
#pragma unroll
        for (int pass = 0; pass < 4; ++pass) {
            int ci = c0 + pass * 16;
            lds[px * 68 + ci] = sb[ci * HW + p0 + px];
        }
    }
    __syncthreads();
    if (t < 128) {
        int px = t >> 3, q = t & 7;
        bf8_t vh, vl;
        f4_t  f0, f1;
#pragma unroll
        for (int j = 0; j < 8; ++j) {
            float a = lds[px * 68 + q * 8 + j];
            bf_t hcast = (bf_t)a;
            vh[j] = hcast;
            vl[j] = (bf_t)(a - (float)hcast);
            if (j < 4) f0[j] = a; else f1[j - 4] = a;
        }
        long base = (((long)b * 4096 + p0 + px) * 64) + q * 8;
        *(bf8_t*)&dhi[base] = vh;
        *(bf8_t*)&dlo[base] = vl;
        *(f4_t*)&df[base]     = f0;
        *(f4_t*)&df[base + 4] = f1;
    }
}

// ---------------------------------------------------------------------------
// fp32 NHWC buffer -> bf16 NHWC hi/lo (elementwise). grid 256, blk 256, 8/thr.
// ---------------------------------------------------------------------------
__global__ __launch_bounds__(256) void split_flat_kernel(
    int src_off, int hi_off, int lo_off)
{
    const long idx = (long)blockIdx.x * 256 + threadIdx.x;   // 65536 total
    const float* s = g_ws + src_off + idx * 8;
    bf8_t vh, vl;
#pragma unroll
    for (int j = 0; j < 8; ++j) {
        float a = s[j];
        bf_t hcast = (bf_t)a;
        vh[j] = hcast;
        vl[j] = (bf_t)(a - (float)hcast);
    }
    *(bf8_t*)((bf_t*)(g_ws + hi_off) + idx * 8) = vh;
    *(bf8_t*)((bf_t*)(g_ws + lo_off) + idx * 8) = vl;
}

// ---------------------------------------------------------------------------
// Conv weight pack (unchanged): fp32 [Cout][64][K][K] -> bf16 A-frag layout.
// ---------------------------------------------------------------------------
template<int K, int NCOT>
__global__ __launch_bounds__(256) void prep_wA_kernel(const float* __restrict__ wg,
                                                      int aw_off, int Cout) {
    bf_t* aw = (bf_t*)(g_ws + aw_off);
    constexpr int KK = K * K;
    const int total = KK * NCOT * 2 * 64;
    for (int idx = blockIdx.x * 256 + threadIdx.x; idx < total; idx += gridDim.x * 256) {
        int lane = idx & 63;
        int kh   = (idx >> 6) & 1;
        int cot  = (idx >> 7) % NCOT;
        int tap  = idx / (128 * NCOT);
        int co   = cot * 16 + (lane & 15);
        int ci0  = kh * 32 + (lane >> 4) * 8;
        bf8_t v;
#pragma unroll
        for (int j = 0; j < 8; ++j) {
            float f = (co < Cout) ? wg[(co * 64 + ci0 + j) * KK + tap] : 0.f;
            v[j] = (bf_t)f;
        }
        *(bf8_t*)&aw[(long)idx * 8] = v;
    }
}

// ---------------------------------------------------------------------------
// Depthwise weight transpose: [64][KK] -> [KK][64].
// ---------------------------------------------------------------------------
__global__ __launch_bounds__(256) void prep_dwT_kernel(const float* __restrict__ w,
                                                       int dst_off, int KK) {
    int n = KK * 64;
    for (int idx = blockIdx.x * 256 + threadIdx.x; idx < n; idx += gridDim.x * 256) {
        int c = idx & 63, kk = idx >> 6;
        g_ws[dst_off + kk * 64 + c] = w[c * KK + kk];
    }
}

// ---------------------------------------------------------------------------
// MFMA implicit-GEMM conv with hi/lo split input (unchanged structure).
// grid (B*64 rows, 2); block 256.
// ---------------------------------------------------------------------------
template<int K, int DIL, int PAD, int NCOT, int CPG>
__global__ __launch_bounds__(256) void mfma_conv_kernel(
    int hi_off, int lo_off, int aw_off, const float* __restrict__ bias,
    int dst_off, int Cout)
{
    constexpr int COLS = 64 + 2 * PAD;
    const bf_t* shi = (const bf_t*)(g_ws + hi_off);
    const bf_t* slo = (const bf_t*)(g_ws + lo_off);
    const bf_t* aw  = (const bf_t*)(g_ws + aw_off);
    float* dst = g_ws + dst_off;
    __shared__ __align__(16) bf_t lds[2][COLS * 72];

    const int t    = threadIdx.x;
    const int lane = t & 63;
    const int wv   = t >> 6;
    const int b    = blockIdx.x >> 6;
    const int h    = blockIdx.x & 63;
    const int ct0  = blockIdx.y * CPG;

    const int n0 = lane & 15;
    const int kq = lane >> 4;

    f4_t acc[CPG];
#pragma unroll
    for (int i = 0; i < CPG; ++i) acc[i] = (f4_t){0.f, 0.f, 0.f, 0.f};

    for (int ky = 0; ky < K; ++ky) {
        const int ih = h - PAD + ky * DIL;
        __syncthreads();
        if ((unsigned)ih < 64u) {
            const long rowb = ((long)b * 4096 + ih * 64) * 64;
            for (int c = t; c < COLS * 8; c += 256) {
                int col = c >> 3, q = c & 7;
                int iw = col - PAD;
                bf8_t vh, vl;
                if ((unsigned)iw < 64u) {
                    vh = *(const bf8_t*)&shi[rowb + iw * 64 + q * 8];
                    vl = *(const bf8_t*)&slo[rowb + iw * 64 + q * 8];
                } else { vh = bf8_zero(); vl = bf8_zero(); }
                *(bf8_t*)&lds[0][col * 72 + q * 8] = vh;
                *(bf8_t*)&lds[1][col * 72 + q * 8] = vl;
            }
        } else {
            bf8_t z = bf8_zero();
            for (int c = t; c < COLS * 8; c += 256) {
                int col = c >> 3, q = c & 7;
                *(bf8_t*)&lds[0][col * 72 + q * 8] = z;
                *(bf8_t*)&lds[1][col * 72 + q * 8] = z;
            }
        }
        __syncthreads();
#pragma unroll
        for (int kx = 0; kx < K; ++kx) {
            const int tap = ky * K + kx;
            bf8_t afr[CPG][2];
#pragma unroll
            for (int ct = 0; ct < CPG; ++ct)
#pragma unroll
                for (int kh = 0; kh < 2; ++kh)
                    afr[ct][kh] = *(const bf8_t*)
                        &aw[((((long)tap * NCOT + ct0 + ct) * 2 + kh) * 64 + lane) * 8];
            const int colb = (wv * 16 + n0 + kx * DIL) * 72;
#pragma unroll
            for (int kh = 0; kh < 2; ++kh) {
                const bf8_t bh = *(const bf8_t*)&lds[0][colb + kh * 32 + kq * 8];
                const bf8_t bl = *(const bf8_t*)&lds[1][colb + kh * 32 + kq * 8];
#pragma unroll
                for (int ct = 0; ct < CPG; ++ct) {
                    acc[ct] = __builtin_amdgcn_mfma_f32_16x16x32_bf16(
                        afr[ct][kh], bh, acc[ct], 0, 0, 0);
                    acc[ct] = __builtin_amdgcn_mfma_f32_16x16x32_bf16(
                        afr[ct][kh], bl, acc[ct], 0, 0, 0);
                }
            }
        }
    }

    const int w = wv * 16 + n0;
#pragma unroll
    for (int ct = 0; ct < CPG; ++ct) {
#pragma unroll
        for (int r = 0; r < 4; ++r) {
            int co = (ct0 + ct) * 16 + kq * 4 + r;
            if (co < Cout)
                dst[((long)b * Cout + co) * HW + h * 64 + w] = acc[ct][r] + bias[co];
        }
    }
}

// ---------------------------------------------------------------------------
// Deformable depthwise, NHWC: lane = channel, one pixel per wave.
// All 4 bilinear corner loads are contiguous 256B (coalesced); offsets and
// index math are computed once per wave (amortized over 64 channels).
// grid 2048, block 256 (4 waves = 4 pixels). Arithmetic per output identical
// to previous rounds -> bitwise-same results.
// ---------------------------------------------------------------------------
template<int K>
__global__ __launch_bounds__(256) void deform_kernel(
    int src_off, int off_off, int dwt_off, int dst_off, int pad, int dil)
{
    constexpr int KK = K * K;
    const int t  = threadIdx.x;
    const int c  = t & 63;
    const int pg = blockIdx.x * 4 + (t >> 6);
    const int b  = pg >> 12;
    const int p  = pg & 4095;
    const int h  = p >> 6;
    const int w  = p & 63;

    const float* sb = g_ws + src_off + (long)b * (4096 * 64);
    const float* ob = g_ws + off_off + ((long)b * (2 * KK)) * HW + p;
    const float* wt = g_ws + dwt_off;

    float acc = 0.f;

    for (int ky = 0; ky < K; ++ky) {
        const float pyb = (float)(h - pad + ky * dil);
#pragma unroll
        for (int kx = 0; kx < K; ++kx) {
            const int kk = ky * K + kx;
            const float oy = ob[(2 * kk) * HW];
            const float ox = ob[(2 * kk + 1) * HW];
            const float py = oy + pyb;
            const float px = ox + (float)(w - pad + kx * dil);
            const float fy = floorf(py), fx = floorf(px);
            const float ly = py - fy,    lx = px - fx;
            const int y0 = (int)fy, x0 = (int)fx;
            const int y1 = y0 + 1,  x1 = x0 + 1;
            const float vy0 = ((unsigned)y0 < 64u) ? 1.f : 0.f;
            const float vy1 = ((unsigned)y1 < 64u) ? 1.f : 0.f;
            const float vx0 = ((unsigned)x0 < 64u) ? 1.f : 0.f;
            const float vx1 = ((unsigned)x1 < 64u) ? 1.f : 0.f;
            const float w00 = (1.f - ly) * (1.f - lx) * vy0 * vx0;
            const float w01 = (1.f - ly) * lx         * vy0 * vx1;
            const float w10 = ly         * (1.f - lx) * vy1 * vx0;
            const float w11 = ly         * lx         * vy1 * vx1;
            const int y0c = min(max(y0, 0), 63), y1c = min(max(y1, 0), 63);
            const int x0c = min(max(x0, 0), 63), x1c = min(max(x1, 0), 63);
            const float* s00 = sb + (long)(y0c * 64 + x0c) * 64;
            const float* s01 = sb + (long)(y0c * 64 + x1c) * 64;
            const float* s10 = sb + (long)(y1c * 64 + x0c) * 64;
            const float* s11 = sb + (long)(y1c * 64 + x1c) * 64;
            float val = w00 * s00[c] + w01 * s01[c]
                      + w10 * s10[c] + w11 * s11[c];
            acc = fmaf(wt[kk * 64 + c], val, acc);
        }
    }

    g_ws[dst_off + ((long)b * 4096 + p) * 64 + c] = acc;
}

// ---------------------------------------------------------------------------
// Final: per-branch 1x1 conv (+bias), then out = x * result.
// Reads NHWC activations via LDS transpose tile; fp32 NCHW out.
// grid (64 px-tiles, 4, B); block 256.
// ---------------------------------------------------------------------------
__global__ __launch_bounds__(256) void final_kernel(
    const float* __restrict__ x,
    int aA_off, int aB_off,
    const float* __restrict__ w1, const float* __restrict__ b1,
    const float* __restrict__ w2, const float* __restrict__ b2,
    float* __restrict__ out)
{
    __shared__ float atile[64 * 65];
    __shared__ float wlds[64 * 32];
    const int t  = threadIdx.x;
    const int p0 = blockIdx.x * 64;
    const int by = blockIdx.y;          // 0..3
    const int b  = blockIdx.z;
    const bool brB  = (by >> 1) != 0;
    const int  cbase = (by & 1) * 32;
    const float* a  = g_ws + (brB ? aB_off : aA_off) + (long)b * (4096 * 64);
    const float* wg = brB ? w2 : w1;
    const float* bg = brB ? b2 : b1;

    {   // load 64px x 64ci NHWC tile, coalesced (lane = ci)
        const int ci = t & 63;
        const int pxg = (t >> 6) * 16;
#pragma unroll
        for (int i = 0; i < 16; ++i) {
            int px = pxg + i;
            atile[px * 65 + ci] = a[(long)(p0 + px) * 64 + ci];
        }
    }
    for (int e = t; e < 2048; e += 256) {
        int col = e & 31, ci = e >> 5;
        wlds[ci * 32 + col] = wg[(cbase + col) * 64 + ci];
    }
    __syncthreads();

    const int px  = t & 63;
    const int cog = t >> 6;
    float acc[8] = {0, 0, 0, 0, 0, 0, 0, 0};
    for (int ci = 0; ci < 64; ++ci) {
        const float av = atile[px * 65 + ci];
        const float* wr = &wlds[ci * 32 + cog * 8];
#pragma unroll
        for (int j = 0; j < 8; ++j) acc[j] = fmaf(av, wr[j], acc[j]);
    }

    const int p = p0 + px;
#pragma unroll
    for (int j = 0; j < 8; ++j) {
        const int co = cbase + cog * 8 + j;       // within branch
        const int cg = (brB ? 64 : 0) + co;       // global channel
        const long o = ((long)b * 128 + cg) * HW + p;
        out[o] = (acc[j] + bg[co]) * x[o];
    }
}

// ---------------------------------------------------------------------------
extern "C" void kernel_launch(void* const* d_in, const int* in_sizes, int n_in,
                              void* d_out, int out_size, void* d_ws, size_t ws_size,
                              hipStream_t stream) {
    const float* x         = (const float*)d_in[0];
    const float* cv0_off_w = (const float*)d_in[1];
    const float* cv0_off_b = (const float*)d_in[2];
    const float* cv0_w     = (const float*)d_in[3];
    const float* cvs_off_w = (const float*)d_in[4];
    const float* cvs_off_b = (const float*)d_in[5];
    const float* cvs_w     = (const float*)d_in[6];
    const float* c0_off_w  = (const float*)d_in[7];
    const float* c0_off_b  = (const float*)d_in[8];
    const float* c0_w      = (const float*)d_in[9];
    const float* cs_off_w  = (const float*)d_in[10];
    const float* cs_off_b  = (const float*)d_in[11];
    const float* cs_w      = (const float*)d_in[12];
    const float* conv1_w   = (const float*)d_in[13];
    const float* conv1_b   = (const float*)d_in[14];
    const float* conv2_w   = (const float*)d_in[15];
    const float* conv2_b   = (const float*)d_in[16];
    float* out = (float*)d_out;
    (void)d_ws; (void)ws_size;

    const int XB = 128 * HW;

    // weight packs (tiny)
    prep_wA_kernel<3, 2><<<dim3(9),   256, 0, stream>>>(cv0_off_w, AW_A1, 18);
    prep_wA_kernel<5, 4><<<dim3(50),  256, 0, stream>>>(c0_off_w,  AW_B1, 50);
    prep_wA_kernel<5, 4><<<dim3(50),  256, 0, stream>>>(cvs_off_w, AW_A2, 50);
    prep_wA_kernel<7, 8><<<dim3(196), 256, 0, stream>>>(cs_off_w,  AW_B2, 98);
    prep_dwT_kernel<<<dim3(3),  256, 0, stream>>>(cv0_w, DW_A1, 9);
    prep_dwT_kernel<<<dim3(7),  256, 0, stream>>>(c0_w,  DW_B1, 25);
    prep_dwT_kernel<<<dim3(7),  256, 0, stream>>>(cvs_w, DW_A2, 25);
    prep_dwT_kernel<<<dim3(13), 256, 0, stream>>>(cs_w,  DW_B2, 49);

    // x branches -> bf16 hi/lo + fp32, all NHWC
    split_x_kernel<<<dim3(2, 256), 256, 0, stream>>>(x,           XB, XA_HI, XA_LO, XA_F32);
    split_x_kernel<<<dim3(2, 256), 256, 0, stream>>>(x + 64 * HW, XB, XB_HI, XB_LO, XB_F32);

    // stage 1: offset convs (MFMA)
    mfma_conv_kernel<3, 1, 1, 2, 1><<<dim3(128, 2), 256, 0, stream>>>(
        XA_HI, XA_LO, AW_A1, cv0_off_b, OFF_A, 18);
    mfma_conv_kernel<5, 1, 2, 4, 2><<<dim3(128, 2), 256, 0, stream>>>(
        XB_HI, XB_LO, AW_B1, c0_off_b, OFF_B, 50);

    // stage 1: deformable depthwise (NHWC coalesced)
    deform_kernel<3><<<dim3(2048), 256, 0, stream>>>(XA_F32, OFF_A, DW_A1, A1_F32, 1, 1);
    deform_kernel<5><<<dim3(2048), 256, 0, stream>>>(XB_F32, OFF_B, DW_B1, B1_F32, 2, 1);

    // stage-1 activations -> bf16 hi/lo
    split_flat_kernel<<<dim3(256), 256, 0, stream>>>(A1_F32, A1_HI, A1_LO);
    split_flat_kernel<<<dim3(256), 256, 0, stream>>>(B1_F32, B1_HI, B1_LO);

    // stage 2: offset convs (MFMA)
    mfma_conv_kernel<5, 3, 6, 4, 2><<<dim3(128, 2), 256, 0, stream>>>(
        A1_HI, A1_LO, AW_A2, cvs_off_b, OFF_A, 50);
    mfma_conv_kernel<7, 3, 9, 8, 4><<<dim3(128, 2), 256, 0, stream>>>(
        B1_HI, B1_LO, AW_B2, cs_off_b, OFF_B, 98);

    // stage 2: deformable depthwise
    deform_kernel<5><<<dim3(2048), 256, 0, stream>>>(A1_F32, OFF_A, DW_A2, A2_F32, 6, 3);
    deform_kernel<7><<<dim3(2048), 256, 0, stream>>>(B1_F32, OFF_B, DW_B2, B2_F32, 9, 3);

    // 1x1 convs + gating multiply
    final_kernel<<<dim3(64, 4, 2), 256, 0, stream>>>(
        x, A2_F32, B2_F32, conv1_w, conv1_b, conv2_w, conv2_b, out);
}

// Round 8
// 252.913 us; speedup vs baseline: 1.4668x; 1.1545x over previous
//
#include <hip/hip_runtime.h>
#include <hip/hip_bf16.h>

#define HW   4096

typedef __bf16 bf_t;
typedef __bf16 bf8_t __attribute__((ext_vector_type(8)));
typedef float  f4_t  __attribute__((ext_vector_type(4)));
typedef int    i4_t  __attribute__((ext_vector_type(4)));

// Static device workspace (element offsets into g_ws, in floats):
#define OFF_A    0              // 2*50*HW NCHW offset maps
#define OFF_B    409600         // 2*98*HW
#define A1_F32   1212416        // NHWC fp32 [b][4096][64] = 524288 each
#define B1_F32   1736704
#define A2_F32   2260992
#define B2_F32   2785280
#define XA_F32   3309568
#define XB_F32   3833856
#define XA_HI    4358144        // bf16 NHWC = 262144 floats each
#define XA_LO    4620288
#define XB_HI    4882432
#define XB_LO    5144576
#define A1_HI    5406720
#define A1_LO    5668864
#define B1_HI    5931008
#define B1_LO    6193152
#define AW_A1    6455296        // conv weight packs (bf16 A-frag)
#define AW_B1    6464512
#define AW_A2    6515712
#define AW_B2    6566912
#define DW_A1    6767616        // depthwise weights transposed [KK][64]
#define DW_B1    6768192
#define DW_A2    6769792
#define DW_B2    6771392
// Precomputed bilinear records (32B = float4 wgt + int4 byte-offsets), reused per stage:
#define PRE_S1_A 6774528        // k3: 2*9*4096*8  = 589824
#define PRE_S1_B 7364352        // k5: 2*25*4096*8 = 1638400
#define PRE_S2_A 6774528        // k5: 1638400
#define PRE_S2_B 8412928        // k7: 2*49*4096*8 = 3211264
#define WS_TOT   11624192

__device__ __align__(16) float g_ws[WS_TOT];

__device__ __forceinline__ bf8_t bf8_zero() {
    bf8_t v;
#pragma unroll
    for (int j = 0; j < 8; ++j) v[j] = (bf_t)0.f;
    return v;
}

// ---------------------------------------------------------------------------
// All weight prep in ONE launch (335 blocks), ranges dispatch to helpers.
// ---------------------------------------------------------------------------
__device__ __forceinline__ void prep_wA_dev(const float* wg, int aw_off,
                                            int Cout, int K, int NCOT, int lb) {
    const int KK = K * K;
    const int total = KK * NCOT * 128;
    const int idx = lb * 256 + threadIdx.x;
    if (idx >= total) return;
    bf_t* aw = (bf_t*)(g_ws + aw_off);
    int lane = idx & 63;
    int kh   = (idx >> 6) & 1;
    int cot  = (idx >> 7) % NCOT;
    int tap  = idx / (128 * NCOT);
    int co   = cot * 16 + (lane & 15);
    int ci0  = kh * 32 + (lane >> 4) * 8;
    bf8_t v;
#pragma unroll
    for (int j = 0; j < 8; ++j) {
        float f = (co < Cout) ? wg[(co * 64 + ci0 + j) * KK + tap] : 0.f;
        v[j] = (bf_t)f;
    }
    *(bf8_t*)&aw[(long)idx * 8] = v;
}

__device__ __forceinline__ void prep_dwT_dev(const float* w, int dst_off,
                                             int KK, int lb) {
    const int idx = lb * 256 + threadIdx.x;
    if (idx < KK * 64) {
        int c = idx & 63, kk = idx >> 6;
        g_ws[dst_off + kk * 64 + c] = w[c * KK + kk];
    }
}

__global__ __launch_bounds__(256) void prep_all_kernel(
    const float* cv0_off_w, const float* c0_off_w,
    const float* cvs_off_w, const float* cs_off_w,
    const float* cv0_w, const float* c0_w,
    const float* cvs_w, const float* cs_w)
{
    const int bi = blockIdx.x;
    if      (bi < 9)   prep_wA_dev(cv0_off_w, AW_A1, 18, 3, 2, bi);
    else if (bi < 59)  prep_wA_dev(c0_off_w,  AW_B1, 50, 5, 4, bi - 9);
    else if (bi < 109) prep_wA_dev(cvs_off_w, AW_A2, 50, 5, 4, bi - 59);
    else if (bi < 305) prep_wA_dev(cs_off_w,  AW_B2, 98, 7, 8, bi - 109);
    else if (bi < 308) prep_dwT_dev(cv0_w, DW_A1, 9,  bi - 305);
    else if (bi < 315) prep_dwT_dev(c0_w,  DW_B1, 25, bi - 308);
    else if (bi < 322) prep_dwT_dev(cvs_w, DW_A2, 25, bi - 315);
    else               prep_dwT_dev(cs_w,  DW_B2, 49, bi - 322);
}

// ---------------------------------------------------------------------------
// x NCHW -> bf16 NHWC hi/lo + fp32 NHWC, both branches in one launch.
// grid (4, 256): blockIdx.x = b | (branch<<1).
// ---------------------------------------------------------------------------
__global__ __launch_bounds__(256) void split_x_kernel(const float* __restrict__ x)
{
    const int bi = blockIdx.x;
    const int b  = bi & 1;
    const int br = bi >> 1;
    const float* sb = x + (long)b * (128 * HW) + (long)br * (64 * HW);
    bf_t*  dhi = (bf_t*)(g_ws + (br ? XB_HI : XA_HI));
    bf_t*  dlo = (bf_t*)(g_ws + (br ? XB_LO : XA_LO));
    float* df  = g_ws + (br ? XB_F32 : XA_F32);
    __shared__ float lds[16 * 68];
    const int p0 = blockIdx.y * 16;
    const int t  = threadIdx.x;
    {
        const int px = t & 15;
        const int c0 = t >> 4;
#pragma unroll
        for (int pass = 0; pass < 4; ++pass) {
            int ci = c0 + pass * 16;
            lds[px * 68 + ci] = sb[ci * HW + p0 + px];
        }
    }
    __syncthreads();
    if (t < 128) {
        int px = t >> 3, q = t & 7;
        bf8_t vh, vl;
        f4_t  f0, f1;
#pragma unroll
        for (int j = 0; j < 8; ++j) {
            float a = lds[px * 68 + q * 8 + j];
            bf_t hcast = (bf_t)a;
            vh[j] = hcast;
            vl[j] = (bf_t)(a - (float)hcast);
            if (j < 4) f0[j] = a; else f1[j - 4] = a;
        }
        long base = (((long)b * 4096 + p0 + px) * 64) + q * 8;
        *(bf8_t*)&dhi[base] = vh;
        *(bf8_t*)&dlo[base] = vl;
        *(f4_t*)&df[base]     = f0;
        *(f4_t*)&df[base + 4] = f1;
    }
}

// ---------------------------------------------------------------------------
// MFMA implicit-GEMM conv with hi/lo split input (unchanged).
// grid (B*64 rows, 2); block 256.
// ---------------------------------------------------------------------------
template<int K, int DIL, int PAD, int NCOT, int CPG>
__global__ __launch_bounds__(256) void mfma_conv_kernel(
    int hi_off, int lo_off, int aw_off, const float* __restrict__ bias,
    int dst_off, int Cout)
{
    constexpr int COLS = 64 + 2 * PAD;
    const bf_t* shi = (const bf_t*)(g_ws + hi_off);
    const bf_t* slo = (const bf_t*)(g_ws + lo_off);
    const bf_t* aw  = (const bf_t*)(g_ws + aw_off);
    float* dst = g_ws + dst_off;
    __shared__ __align__(16) bf_t lds[2][COLS * 72];

    const int t    = threadIdx.x;
    const int lane = t & 63;
    const int wv   = t >> 6;
    const int b    = blockIdx.x >> 6;
    const int h    = blockIdx.x & 63;
    const int ct0  = blockIdx.y * CPG;

    const int n0 = lane & 15;
    const int kq = lane >> 4;

    f4_t acc[CPG];
#pragma unroll
    for (int i = 0; i < CPG; ++i) acc[i] = (f4_t){0.f, 0.f, 0.f, 0.f};

    for (int ky = 0; ky < K; ++ky) {
        const int ih = h - PAD + ky * DIL;
        __syncthreads();
        if ((unsigned)ih < 64u) {
            const long rowb = ((long)b * 4096 + ih * 64) * 64;
            for (int c = t; c < COLS * 8; c += 256) {
                int col = c >> 3, q = c & 7;
                int iw = col - PAD;
                bf8_t vh, vl;
                if ((unsigned)iw < 64u) {
                    vh = *(const bf8_t*)&shi[rowb + iw * 64 + q * 8];
                    vl = *(const bf8_t*)&slo[rowb + iw * 64 + q * 8];
                } else { vh = bf8_zero(); vl = bf8_zero(); }
                *(bf8_t*)&lds[0][col * 72 + q * 8] = vh;
                *(bf8_t*)&lds[1][col * 72 + q * 8] = vl;
            }
        } else {
            bf8_t z = bf8_zero();
            for (int c = t; c < COLS * 8; c += 256) {
                int col = c >> 3, q = c & 7;
                *(bf8_t*)&lds[0][col * 72 + q * 8] = z;
                *(bf8_t*)&lds[1][col * 72 + q * 8] = z;
            }
        }
        __syncthreads();
#pragma unroll
        for (int kx = 0; kx < K; ++kx) {
            const int tap = ky * K + kx;
            bf8_t afr[CPG][2];
#pragma unroll
            for (int ct = 0; ct < CPG; ++ct)
#pragma unroll
                for (int kh = 0; kh < 2; ++kh)
                    afr[ct][kh] = *(const bf8_t*)
                        &aw[((((long)tap * NCOT + ct0 + ct) * 2 + kh) * 64 + lane) * 8];
            const int colb = (wv * 16 + n0 + kx * DIL) * 72;
#pragma unroll
            for (int kh = 0; kh < 2; ++kh) {
                const bf8_t bh = *(const bf8_t*)&lds[0][colb + kh * 32 + kq * 8];
                const bf8_t bl = *(const bf8_t*)&lds[1][colb + kh * 32 + kq * 8];
#pragma unroll
                for (int ct = 0; ct < CPG; ++ct) {
                    acc[ct] = __builtin_amdgcn_mfma_f32_16x16x32_bf16(
                        afr[ct][kh], bh, acc[ct], 0, 0, 0);
                    acc[ct] = __builtin_amdgcn_mfma_f32_16x16x32_bf16(
                        afr[ct][kh], bl, acc[ct], 0, 0, 0);
                }
            }
        }
    }

    const int w = wv * 16 + n0;
#pragma unroll
    for (int ct = 0; ct < CPG; ++ct) {
#pragma unroll
        for (int r = 0; r < 4; ++r) {
            int co = (ct0 + ct) * 16 + kq * 4 + r;
            if (co < Cout)
                dst[((long)b * Cout + co) * HW + h * 64 + w] = acc[ct][r] + bias[co];
        }
    }
}

// ---------------------------------------------------------------------------
// Deform phase A: per-(b,tap,pixel) bilinear weights + clamped corner BYTE
// offsets, lane = pixel (coalesced). Record: float4 wgt + int4 offs (32B).
// Identical arithmetic to previous in-sampler math -> bitwise-same weights.
// ---------------------------------------------------------------------------
template<int K>
__device__ __forceinline__ void precomp_dev(int off_off, int pre_off,
                                            int pad, int dil, int lb) {
    constexpr int KK = K * K;
    const int idx = lb * 256 + threadIdx.x;      // < 2*KK*4096 (grid-exact)
    const int p  = idx & 4095;
    const int r  = idx >> 12;
    const int kk = r % KK;
    const int b  = r / KK;
    const int h  = p >> 6, w = p & 63;

    const float oy = g_ws[off_off + ((long)(b * 2 * KK + 2 * kk)) * HW + p];
    const float ox = g_ws[off_off + ((long)(b * 2 * KK + 2 * kk + 1)) * HW + p];
    const float py = oy + (float)(h - pad + (kk / K) * dil);
    const float px = ox + (float)(w - pad + (kk % K) * dil);
    const float fy = floorf(py), fx = floorf(px);
    const float ly = py - fy,    lx = px - fx;
    const int y0 = (int)fy, x0 = (int)fx;
    const int y1 = y0 + 1,  x1 = x0 + 1;
    const float vy0 = ((unsigned)y0 < 64u) ? 1.f : 0.f;
    const float vy1 = ((unsigned)y1 < 64u) ? 1.f : 0.f;
    const float vx0 = ((unsigned)x0 < 64u) ? 1.f : 0.f;
    const float vx1 = ((unsigned)x1 < 64u) ? 1.f : 0.f;
    const float w00 = (1.f - ly) * (1.f - lx) * vy0 * vx0;
    const float w01 = (1.f - ly) * lx         * vy0 * vx1;
    const float w10 = ly         * (1.f - lx) * vy1 * vx0;
    const float w11 = ly         * lx         * vy1 * vx1;
    const int y0c = min(max(y0, 0), 63), y1c = min(max(y1, 0), 63);
    const int x0c = min(max(x0, 0), 63), x1c = min(max(x1, 0), 63);
    const int i00 = (y0c * 64 + x0c) * 256, i01 = (y0c * 64 + x1c) * 256;
    const int i10 = (y1c * 64 + x0c) * 256, i11 = (y1c * 64 + x1c) * 256;

    const long rb = (long)idx * 8;
    f4_t wv = {w00, w01, w10, w11};
    i4_t iv = {i00, i01, i10, i11};
    *(f4_t*)&g_ws[pre_off + rb]     = wv;
    *(i4_t*)&g_ws[pre_off + rb + 4] = iv;
}

template<int KA, int KB>
__global__ __launch_bounds__(256) void precomp_kernel(
    int offA, int preA, int padA, int dilA,
    int offB, int preB, int padB, int dilB, int blocksA)
{
    const int bi = blockIdx.x;
    if (bi < blocksA) precomp_dev<KA>(offA, preA, padA, dilA, bi);
    else              precomp_dev<KB>(offB, preB, padB, dilB, bi - blocksA);
}

// ---------------------------------------------------------------------------
// Deform phase B (sampler): lane = channel, wave = pixel. Per tap: one
// wave-uniform 32B record (scalarized via readfirstlane) + 4 coalesced corner
// loads + 5 VALU. Both branches in one launch (blocks [0,2048) = A).
// Optionally emits bf16 hi/lo (replaces split_flat).
// ---------------------------------------------------------------------------
template<int WRITE_HILO>
__global__ __launch_bounds__(256) void sample_kernel(
    int srcA, int preA, int dwtA, int dstA, int hiA, int loA, int kkA,
    int srcB, int preB, int dwtB, int dstB, int hiB, int loB, int kkB)
{
    const int t = threadIdx.x;
    int bx = blockIdx.x;
    int src_off, pre_off, dwt_off, dst_off, hi_off, lo_off, KK;
    if (bx < 2048) {
        src_off = srcA; pre_off = preA; dwt_off = dwtA;
        dst_off = dstA; hi_off = hiA; lo_off = loA; KK = kkA;
    } else {
        bx -= 2048;
        src_off = srcB; pre_off = preB; dwt_off = dwtB;
        dst_off = dstB; hi_off = hiB; lo_off = loB; KK = kkB;
    }
    const int c  = t & 63;
    const int pg = bx * 4 + (t >> 6);
    const int b  = pg >> 12;
    const int p  = pg & 4095;

    const char* sb = (const char*)(g_ws + src_off + ((long)b << 18)) + (c << 2);
    const float* wtp = g_ws + dwt_off + c;
    int roff = (((b * KK) << 12) | p) * 8;
    roff = __builtin_amdgcn_readfirstlane(roff);

    float acc = 0.f;
    for (int kk = 0; kk < KK; ++kk) {
        const float* rp = g_ws + pre_off + roff;
        const f4_t wq = *(const f4_t*)rp;
        const i4_t iq = *(const i4_t*)(rp + 4);
        const float v00 = *(const float*)(sb + iq.x);
        const float v01 = *(const float*)(sb + iq.y);
        const float v10 = *(const float*)(sb + iq.z);
        const float v11 = *(const float*)(sb + iq.w);
        const float val = wq.x * v00 + wq.y * v01 + wq.z * v10 + wq.w * v11;
        acc = fmaf(*wtp, val, acc);
        roff += 4096 * 8;
        wtp  += 64;
    }

    const long ob = ((long)b * 4096 + p) * 64 + c;
    g_ws[dst_off + ob] = acc;
    if (WRITE_HILO) {
        bf_t h16 = (bf_t)acc;
        ((bf_t*)(g_ws + hi_off))[ob] = h16;
        ((bf_t*)(g_ws + lo_off))[ob] = (bf_t)(acc - (float)h16);
    }
}

// ---------------------------------------------------------------------------
// Final: per-branch 1x1 conv (+bias), then out = x * result (unchanged).
// ---------------------------------------------------------------------------
__global__ __launch_bounds__(256) void final_kernel(
    const float* __restrict__ x,
    int aA_off, int aB_off,
    const float* __restrict__ w1, const float* __restrict__ b1,
    const float* __restrict__ w2, const float* __restrict__ b2,
    float* __restrict__ out)
{
    __shared__ float atile[64 * 65];
    __shared__ float wlds[64 * 32];
    const int t  = threadIdx.x;
    const int p0 = blockIdx.x * 64;
    const int by = blockIdx.y;
    const int b  = blockIdx.z;
    const bool brB  = (by >> 1) != 0;
    const int  cbase = (by & 1) * 32;
    const float* a  = g_ws + (brB ? aB_off : aA_off) + (long)b * (4096 * 64);
    const float* wg = brB ? w2 : w1;
    const float* bg = brB ? b2 : b1;

    {
        const int ci = t & 63;
        const int pxg = (t >> 6) * 16;
#pragma unroll
        for (int i = 0; i < 16; ++i) {
            int px = pxg + i;
            atile[px * 65 + ci] = a[(long)(p0 + px) * 64 + ci];
        }
    }
    for (int e = t; e < 2048; e += 256) {
        int col = e & 31, ci = e >> 5;
        wlds[ci * 32 + col] = wg[(cbase + col) * 64 + ci];
    }
    __syncthreads();

    const int px  = t & 63;
    const int cog = t >> 6;
    float acc[8] = {0, 0, 0, 0, 0, 0, 0, 0};
    for (int ci = 0; ci < 64; ++ci) {
        const float av = atile[px * 65 + ci];
        const float* wr = &wlds[ci * 32 + cog * 8];
#pragma unroll
        for (int j = 0; j < 8; ++j) acc[j] = fmaf(av, wr[j], acc[j]);
    }

    const int p = p0 + px;
#pragma unroll
    for (int j = 0; j < 8; ++j) {
        const int co = cbase + cog * 8 + j;
        const int cg = (brB ? 64 : 0) + co;
        const long o = ((long)b * 128 + cg) * HW + p;
        out[o] = (acc[j] + bg[co]) * x[o];
    }
}

// ---------------------------------------------------------------------------
extern "C" void kernel_launch(void* const* d_in, const int* in_sizes, int n_in,
                              void* d_out, int out_size, void* d_ws, size_t ws_size,
                              hipStream_t stream) {
    const float* x         = (const float*)d_in[0];
    const float* cv0_off_w = (const float*)d_in[1];
    const float* cv0_off_b = (const float*)d_in[2];
    const float* cv0_w     = (const float*)d_in[3];
    const float* cvs_off_w = (const float*)d_in[4];
    const float* cvs_off_b = (const float*)d_in[5];
    const float* cvs_w     = (const float*)d_in[6];
    const float* c0_off_w  = (const float*)d_in[7];
    const float* c0_off_b  = (const float*)d_in[8];
    const float* c0_w      = (const float*)d_in[9];
    const float* cs_off_w  = (const float*)d_in[10];
    const float* cs_off_b  = (const float*)d_in[11];
    const float* cs_w      = (const float*)d_in[12];
    const float* conv1_w   = (const float*)d_in[13];
    const float* conv1_b   = (const float*)d_in[14];
    const float* conv2_w   = (const float*)d_in[15];
    const float* conv2_b   = (const float*)d_in[16];
    float* out = (float*)d_out;
    (void)d_ws; (void)ws_size;

    // 1: all weight prep
    prep_all_kernel<<<dim3(335), 256, 0, stream>>>(
        cv0_off_w, c0_off_w, cvs_off_w, cs_off_w, cv0_w, c0_w, cvs_w, cs_w);

    // 2: x -> NHWC fp32 + bf16 hi/lo (both branches)
    split_x_kernel<<<dim3(4, 256), 256, 0, stream>>>(x);

    // 3-4: stage-1 offset convs (MFMA)
    mfma_conv_kernel<3, 1, 1, 2, 1><<<dim3(128, 2), 256, 0, stream>>>(
        XA_HI, XA_LO, AW_A1, cv0_off_b, OFF_A, 18);
    mfma_conv_kernel<5, 1, 2, 4, 2><<<dim3(128, 2), 256, 0, stream>>>(
        XB_HI, XB_LO, AW_B1, c0_off_b, OFF_B, 50);

    // 5: stage-1 bilinear precompute (both branches)
    precomp_kernel<3, 5><<<dim3(1088), 256, 0, stream>>>(
        OFF_A, PRE_S1_A, 1, 1, OFF_B, PRE_S1_B, 2, 1, 288);

    // 6: stage-1 sampling (+ hi/lo emit)
    sample_kernel<1><<<dim3(4096), 256, 0, stream>>>(
        XA_F32, PRE_S1_A, DW_A1, A1_F32, A1_HI, A1_LO, 9,
        XB_F32, PRE_S1_B, DW_B1, B1_F32, B1_HI, B1_LO, 25);

    // 7-8: stage-2 offset convs (MFMA)
    mfma_conv_kernel<5, 3, 6, 4, 2><<<dim3(128, 2), 256, 0, stream>>>(
        A1_HI, A1_LO, AW_A2, cvs_off_b, OFF_A, 50);
    mfma_conv_kernel<7, 3, 9, 8, 4><<<dim3(128, 2), 256, 0, stream>>>(
        B1_HI, B1_LO, AW_B2, cs_off_b, OFF_B, 98);

    // 9: stage-2 bilinear precompute
    precomp_kernel<5, 7><<<dim3(2368), 256, 0, stream>>>(
        OFF_A, PRE_S2_A, 6, 3, OFF_B, PRE_S2_B, 9, 3, 800);

    // 10: stage-2 sampling
    sample_kernel<0><<<dim3(4096), 256, 0, stream>>>(
        A1_F32, PRE_S2_A, DW_A2, A2_F32, 0, 0, 25,
        B1_F32, PRE_S2_B, DW_B2, B2_F32, 0, 0, 49);

    // 11: 1x1 convs + gating multiply
    final_kernel<<<dim3(64, 4, 2), 256, 0, stream>>>(
        x, A2_F32, B2_F32, conv1_w, conv1_b, conv2_w, conv2_b, out);
}

// Round 9
// 218.665 us; speedup vs baseline: 1.6966x; 1.1566x over previous
//
#include <hip/hip_runtime.h>
#include <hip/hip_bf16.h>

#define HW   4096

typedef __bf16 bf_t;
typedef __bf16 bf8_t __attribute__((ext_vector_type(8)));
typedef float  f4_t  __attribute__((ext_vector_type(4)));
typedef int    i4_t  __attribute__((ext_vector_type(4)));

// Static device workspace (element offsets into g_ws, in floats):
#define OFF_A    0              // 2*50*HW NCHW offset maps
#define OFF_B    409600         // 2*98*HW
#define A1_F32   1212416        // NHWC fp32 [b][4096][64] = 524288 each
#define B1_F32   1736704
#define A2_F32   2260992
#define B2_F32   2785280
#define XA_F32   3309568
#define XB_F32   3833856
#define XA_HI    4358144        // bf16 NHWC = 262144 floats each
#define XA_LO    4620288
#define XB_HI    4882432
#define XB_LO    5144576
#define A1_HI    5406720
#define A1_LO    5668864
#define B1_HI    5931008
#define B1_LO    6193152
#define AW_A1    6455296        // conv weight packs (bf16 A-frag)
#define AW_B1    6464512
#define AW_A2    6515712
#define AW_B2    6566912
#define DW_A1    6767616        // depthwise weights transposed [KK][64]
#define DW_B1    6768192
#define DW_A2    6769792
#define DW_B2    6771392
// Precomputed bilinear records (32B = float4 wgt + int4 byte-offsets), reused per stage:
#define PRE_S1_A 6774528        // k3: 2*9*4096*8  = 589824
#define PRE_S1_B 7364352        // k5: 2*25*4096*8 = 1638400
#define PRE_S2_A 6774528        // k5: 1638400
#define PRE_S2_B 8412928        // k7: 2*49*4096*8 = 3211264
#define WS_TOT   11624192

__device__ __align__(16) float g_ws[WS_TOT];

__device__ __forceinline__ bf8_t bf8_zero() {
    bf8_t v;
#pragma unroll
    for (int j = 0; j < 8; ++j) v[j] = (bf_t)0.f;
    return v;
}

// ---------------------------------------------------------------------------
// All weight prep in ONE launch (335 blocks), ranges dispatch to helpers.
// ---------------------------------------------------------------------------
__device__ __forceinline__ void prep_wA_dev(const float* wg, int aw_off,
                                            int Cout, int K, int NCOT, int lb) {
    const int KK = K * K;
    const int total = KK * NCOT * 128;
    const int idx = lb * 256 + threadIdx.x;
    if (idx >= total) return;
    bf_t* aw = (bf_t*)(g_ws + aw_off);
    int lane = idx & 63;
    int kh   = (idx >> 6) & 1;
    int cot  = (idx >> 7) % NCOT;
    int tap  = idx / (128 * NCOT);
    int co   = cot * 16 + (lane & 15);
    int ci0  = kh * 32 + (lane >> 4) * 8;
    bf8_t v;
#pragma unroll
    for (int j = 0; j < 8; ++j) {
        float f = (co < Cout) ? wg[(co * 64 + ci0 + j) * KK + tap] : 0.f;
        v[j] = (bf_t)f;
    }
    *(bf8_t*)&aw[(long)idx * 8] = v;
}

__device__ __forceinline__ void prep_dwT_dev(const float* w, int dst_off,
                                             int KK, int lb) {
    const int idx = lb * 256 + threadIdx.x;
    if (idx < KK * 64) {
        int c = idx & 63, kk = idx >> 6;
        g_ws[dst_off + kk * 64 + c] = w[c * KK + kk];
    }
}

__global__ __launch_bounds__(256) void prep_all_kernel(
    const float* cv0_off_w, const float* c0_off_w,
    const float* cvs_off_w, const float* cs_off_w,
    const float* cv0_w, const float* c0_w,
    const float* cvs_w, const float* cs_w)
{
    const int bi = blockIdx.x;
    if      (bi < 9)   prep_wA_dev(cv0_off_w, AW_A1, 18, 3, 2, bi);
    else if (bi < 59)  prep_wA_dev(c0_off_w,  AW_B1, 50, 5, 4, bi - 9);
    else if (bi < 109) prep_wA_dev(cvs_off_w, AW_A2, 50, 5, 4, bi - 59);
    else if (bi < 305) prep_wA_dev(cs_off_w,  AW_B2, 98, 7, 8, bi - 109);
    else if (bi < 308) prep_dwT_dev(cv0_w, DW_A1, 9,  bi - 305);
    else if (bi < 315) prep_dwT_dev(c0_w,  DW_B1, 25, bi - 308);
    else if (bi < 322) prep_dwT_dev(cvs_w, DW_A2, 25, bi - 315);
    else               prep_dwT_dev(cs_w,  DW_B2, 49, bi - 322);
}

// ---------------------------------------------------------------------------
// x NCHW -> bf16 NHWC hi/lo + fp32 NHWC, both branches in one launch.
// ---------------------------------------------------------------------------
__global__ __launch_bounds__(256) void split_x_kernel(const float* __restrict__ x)
{
    const int bi = blockIdx.x;
    const int b  = bi & 1;
    const int br = bi >> 1;
    const float* sb = x + (long)b * (128 * HW) + (long)br * (64 * HW);
    bf_t*  dhi = (bf_t*)(g_ws + (br ? XB_HI : XA_HI));
    bf_t*  dlo = (bf_t*)(g_ws + (br ? XB_LO : XA_LO));
    float* df  = g_ws + (br ? XB_F32 : XA_F32);
    __shared__ float lds[16 * 68];
    const int p0 = blockIdx.y * 16;
    const int t  = threadIdx.x;
    {
        const int px = t & 15;
        const int c0 = t >> 4;
#pragma unroll
        for (int pass = 0; pass < 4; ++pass) {
            int ci = c0 + pass * 16;
            lds[px * 68 + ci] = sb[ci * HW + p0 + px];
        }
    }
    __syncthreads();
    if (t < 128) {
        int px = t >> 3, q = t & 7;
        bf8_t vh, vl;
        f4_t  f0, f1;
#pragma unroll
        for (int j = 0; j < 8; ++j) {
            float a = lds[px * 68 + q * 8 + j];
            bf_t hcast = (bf_t)a;
            vh[j] = hcast;
            vl[j] = (bf_t)(a - (float)hcast);
            if (j < 4) f0[j] = a; else f1[j - 4] = a;
        }
        long base = (((long)b * 4096 + p0 + px) * 64) + q * 8;
        *(bf8_t*)&dhi[base] = vh;
        *(bf8_t*)&dlo[base] = vl;
        *(f4_t*)&df[base]     = f0;
        *(f4_t*)&df[base + 4] = f1;
    }
}

// ---------------------------------------------------------------------------
// MFMA implicit-GEMM conv with hi/lo split input.
// grid (B*64 rows, NY); block 256. CPG co-tiles per block.
// ---------------------------------------------------------------------------
template<int K, int DIL, int PAD, int NCOT, int CPG>
__global__ __launch_bounds__(256) void mfma_conv_kernel(
    int hi_off, int lo_off, int aw_off, const float* __restrict__ bias,
    int dst_off, int Cout)
{
    constexpr int COLS = 64 + 2 * PAD;
    const bf_t* shi = (const bf_t*)(g_ws + hi_off);
    const bf_t* slo = (const bf_t*)(g_ws + lo_off);
    const bf_t* aw  = (const bf_t*)(g_ws + aw_off);
    float* dst = g_ws + dst_off;
    __shared__ __align__(16) bf_t lds[2][COLS * 72];

    const int t    = threadIdx.x;
    const int lane = t & 63;
    const int wv   = t >> 6;
    const int b    = blockIdx.x >> 6;
    const int h    = blockIdx.x & 63;
    const int ct0  = blockIdx.y * CPG;

    const int n0 = lane & 15;
    const int kq = lane >> 4;

    f4_t acc[CPG];
#pragma unroll
    for (int i = 0; i < CPG; ++i) acc[i] = (f4_t){0.f, 0.f, 0.f, 0.f};

    for (int ky = 0; ky < K; ++ky) {
        const int ih = h - PAD + ky * DIL;
        __syncthreads();
        if ((unsigned)ih < 64u) {
            const long rowb = ((long)b * 4096 + ih * 64) * 64;
            for (int c = t; c < COLS * 8; c += 256) {
                int col = c >> 3, q = c & 7;
                int iw = col - PAD;
                bf8_t vh, vl;
                if ((unsigned)iw < 64u) {
                    vh = *(const bf8_t*)&shi[rowb + iw * 64 + q * 8];
                    vl = *(const bf8_t*)&slo[rowb + iw * 64 + q * 8];
                } else { vh = bf8_zero(); vl = bf8_zero(); }
                *(bf8_t*)&lds[0][col * 72 + q * 8] = vh;
                *(bf8_t*)&lds[1][col * 72 + q * 8] = vl;
            }
        } else {
            bf8_t z = bf8_zero();
            for (int c = t; c < COLS * 8; c += 256) {
                int col = c >> 3, q = c & 7;
                *(bf8_t*)&lds[0][col * 72 + q * 8] = z;
                *(bf8_t*)&lds[1][col * 72 + q * 8] = z;
            }
        }
        __syncthreads();
#pragma unroll
        for (int kx = 0; kx < K; ++kx) {
            const int tap = ky * K + kx;
            bf8_t afr[CPG][2];
#pragma unroll
            for (int ct = 0; ct < CPG; ++ct)
#pragma unroll
                for (int kh = 0; kh < 2; ++kh)
                    afr[ct][kh] = *(const bf8_t*)
                        &aw[((((long)tap * NCOT + ct0 + ct) * 2 + kh) * 64 + lane) * 8];
            const int colb = (wv * 16 + n0 + kx * DIL) * 72;
#pragma unroll
            for (int kh = 0; kh < 2; ++kh) {
                const bf8_t bh = *(const bf8_t*)&lds[0][colb + kh * 32 + kq * 8];
                const bf8_t bl = *(const bf8_t*)&lds[1][colb + kh * 32 + kq * 8];
#pragma unroll
                for (int ct = 0; ct < CPG; ++ct) {
                    acc[ct] = __builtin_amdgcn_mfma_f32_16x16x32_bf16(
                        afr[ct][kh], bh, acc[ct], 0, 0, 0);
                    acc[ct] = __builtin_amdgcn_mfma_f32_16x16x32_bf16(
                        afr[ct][kh], bl, acc[ct], 0, 0, 0);
                }
            }
        }
    }

    const int w = wv * 16 + n0;
#pragma unroll
    for (int ct = 0; ct < CPG; ++ct) {
#pragma unroll
        for (int r = 0; r < 4; ++r) {
            int co = (ct0 + ct) * 16 + kq * 4 + r;
            if (co < Cout)
                dst[((long)b * Cout + co) * HW + h * 64 + w] = acc[ct][r] + bias[co];
        }
    }
}

// ---------------------------------------------------------------------------
// Deform phase A: per-(b,tap,pixel) bilinear weights + clamped corner BYTE
// offsets, lane = pixel (coalesced). Record: float4 wgt + int4 offs (32B).
// ---------------------------------------------------------------------------
template<int K>
__device__ __forceinline__ void precomp_dev(int off_off, int pre_off,
                                            int pad, int dil, int lb) {
    constexpr int KK = K * K;
    const int idx = lb * 256 + threadIdx.x;      // < 2*KK*4096 (grid-exact)
    const int p  = idx & 4095;
    const int r  = idx >> 12;
    const int kk = r % KK;
    const int b  = r / KK;
    const int h  = p >> 6, w = p & 63;

    const float oy = g_ws[off_off + ((long)(b * 2 * KK + 2 * kk)) * HW + p];
    const float ox = g_ws[off_off + ((long)(b * 2 * KK + 2 * kk + 1)) * HW + p];
    const float py = oy + (float)(h - pad + (kk / K) * dil);
    const float px = ox + (float)(w - pad + (kk % K) * dil);
    const float fy = floorf(py), fx = floorf(px);
    const float ly = py - fy,    lx = px - fx;
    const int y0 = (int)fy, x0 = (int)fx;
    const int y1 = y0 + 1,  x1 = x0 + 1;
    const float vy0 = ((unsigned)y0 < 64u) ? 1.f : 0.f;
    const float vy1 = ((unsigned)y1 < 64u) ? 1.f : 0.f;
    const float vx0 = ((unsigned)x0 < 64u) ? 1.f : 0.f;
    const float vx1 = ((unsigned)x1 < 64u) ? 1.f : 0.f;
    const float w00 = (1.f - ly) * (1.f - lx) * vy0 * vx0;
    const float w01 = (1.f - ly) * lx         * vy0 * vx1;
    const float w10 = ly         * (1.f - lx) * vy1 * vx0;
    const float w11 = ly         * lx         * vy1 * vx1;
    const int y0c = min(max(y0, 0), 63), y1c = min(max(y1, 0), 63);
    const int x0c = min(max(x0, 0), 63), x1c = min(max(x1, 0), 63);
    const int i00 = (y0c * 64 + x0c) * 256, i01 = (y0c * 64 + x1c) * 256;
    const int i10 = (y1c * 64 + x0c) * 256, i11 = (y1c * 64 + x1c) * 256;

    const long rb = (long)idx * 8;
    f4_t wv = {w00, w01, w10, w11};
    i4_t iv = {i00, i01, i10, i11};
    *(f4_t*)&g_ws[pre_off + rb]     = wv;
    *(i4_t*)&g_ws[pre_off + rb + 4] = iv;
}

template<int KA, int KB>
__global__ __launch_bounds__(256) void precomp_kernel(
    int offA, int preA, int padA, int dilA,
    int offB, int preB, int padB, int dilB, int blocksA)
{
    const int bi = blockIdx.x;
    if (bi < blocksA) precomp_dev<KA>(offA, preA, padA, dilA, bi);
    else              precomp_dev<KB>(offB, preB, padB, dilB, bi - blocksA);
}

// ---------------------------------------------------------------------------
// Deform phase B (sampler): lane = channel, wave = pixel. Compile-time KK +
// partial unroll -> batched independent record/gather loads (ILP). XCD-
// contiguous pixel swizzle for src L2 locality.
// ---------------------------------------------------------------------------
template<int KK, int WRITE_HILO>
__device__ __forceinline__ void sample_dev(
    int bx, int src_off, int pre_off, int dwt_off,
    int dst_off, int hi_off, int lo_off)
{
    const int t  = threadIdx.x;
    const int c  = t & 63;
    const int pgi = ((bx & 7) << 8) | (bx >> 3);   // XCD-contiguous chunks
    const int pg  = pgi * 4 + (t >> 6);
    const int b  = pg >> 12;
    const int p  = pg & 4095;

    const char* sb = (const char*)(g_ws + src_off + ((long)b << 18)) + (c << 2);
    const float* wtp = g_ws + dwt_off + c;
    int roff = (((b * KK) << 12) | p) * 8;
    roff = __builtin_amdgcn_readfirstlane(roff);
    const float* pre = g_ws + pre_off + roff;

    float acc = 0.f;
#pragma unroll 8
    for (int kk = 0; kk < KK; ++kk) {
        const float* rp = pre + kk * 32768;
        const f4_t wq = *(const f4_t*)rp;
        const i4_t iq = *(const i4_t*)(rp + 4);
        const float v00 = *(const float*)(sb + iq.x);
        const float v01 = *(const float*)(sb + iq.y);
        const float v10 = *(const float*)(sb + iq.z);
        const float v11 = *(const float*)(sb + iq.w);
        const float val = wq.x * v00 + wq.y * v01 + wq.z * v10 + wq.w * v11;
        acc = fmaf(wtp[kk * 64], val, acc);
    }

    const long ob = ((long)b * 4096 + p) * 64 + c;
    g_ws[dst_off + ob] = acc;
    if (WRITE_HILO) {
        bf_t h16 = (bf_t)acc;
        ((bf_t*)(g_ws + hi_off))[ob] = h16;
        ((bf_t*)(g_ws + lo_off))[ob] = (bf_t)(acc - (float)h16);
    }
}

template<int KKA, int KKB, int WRITE_HILO>
__global__ __launch_bounds__(256) void sample_kernel(
    int srcA, int preA, int dwtA, int dstA, int hiA, int loA,
    int srcB, int preB, int dwtB, int dstB, int hiB, int loB)
{
    const int bx = blockIdx.x;
    if (bx < 2048)
        sample_dev<KKA, WRITE_HILO>(bx, srcA, preA, dwtA, dstA, hiA, loA);
    else
        sample_dev<KKB, WRITE_HILO>(bx - 2048, srcB, preB, dwtB, dstB, hiB, loB);
}

// ---------------------------------------------------------------------------
// Final: per-branch 1x1 conv (+bias), then out = x * result.
// ---------------------------------------------------------------------------
__global__ __launch_bounds__(256) void final_kernel(
    const float* __restrict__ x,
    int aA_off, int aB_off,
    const float* __restrict__ w1, const float* __restrict__ b1,
    const float* __restrict__ w2, const float* __restrict__ b2,
    float* __restrict__ out)
{
    __shared__ float atile[64 * 65];
    __shared__ float wlds[64 * 32];
    const int t  = threadIdx.x;
    const int p0 = blockIdx.x * 64;
    const int by = blockIdx.y;
    const int b  = blockIdx.z;
    const bool brB  = (by >> 1) != 0;
    const int  cbase = (by & 1) * 32;
    const float* a  = g_ws + (brB ? aB_off : aA_off) + (long)b * (4096 * 64);
    const float* wg = brB ? w2 : w1;
    const float* bg = brB ? b2 : b1;

    {
        const int ci = t & 63;
        const int pxg = (t >> 6) * 16;
#pragma unroll
        for (int i = 0; i < 16; ++i) {
            int px = pxg + i;
            atile[px * 65 + ci] = a[(long)(p0 + px) * 64 + ci];
        }
    }
    for (int e = t; e < 2048; e += 256) {
        int col = e & 31, ci = e >> 5;
        wlds[ci * 32 + col] = wg[(cbase + col) * 64 + ci];
    }
    __syncthreads();

    const int px  = t & 63;
    const int cog = t >> 6;
    float acc[8] = {0, 0, 0, 0, 0, 0, 0, 0};
    for (int ci = 0; ci < 64; ++ci) {
        const float av = atile[px * 65 + ci];
        const float* wr = &wlds[ci * 32 + cog * 8];
#pragma unroll
        for (int j = 0; j < 8; ++j) acc[j] = fmaf(av, wr[j], acc[j]);
    }

    const int p = p0 + px;
#pragma unroll
    for (int j = 0; j < 8; ++j) {
        const int co = cbase + cog * 8 + j;
        const int cg = (brB ? 64 : 0) + co;
        const long o = ((long)b * 128 + cg) * HW + p;
        out[o] = (acc[j] + bg[co]) * x[o];
    }
}

// ---------------------------------------------------------------------------
extern "C" void kernel_launch(void* const* d_in, const int* in_sizes, int n_in,
                              void* d_out, int out_size, void* d_ws, size_t ws_size,
                              hipStream_t stream) {
    const float* x         = (const float*)d_in[0];
    const float* cv0_off_w = (const float*)d_in[1];
    const float* cv0_off_b = (const float*)d_in[2];
    const float* cv0_w     = (const float*)d_in[3];
    const float* cvs_off_w = (const float*)d_in[4];
    const float* cvs_off_b = (const float*)d_in[5];
    const float* cvs_w     = (const float*)d_in[6];
    const float* c0_off_w  = (const float*)d_in[7];
    const float* c0_off_b  = (const float*)d_in[8];
    const float* c0_w      = (const float*)d_in[9];
    const float* cs_off_w  = (const float*)d_in[10];
    const float* cs_off_b  = (const float*)d_in[11];
    const float* cs_w      = (const float*)d_in[12];
    const float* conv1_w   = (const float*)d_in[13];
    const float* conv1_b   = (const float*)d_in[14];
    const float* conv2_w   = (const float*)d_in[15];
    const float* conv2_b   = (const float*)d_in[16];
    float* out = (float*)d_out;
    (void)d_ws; (void)ws_size;

    // 1: all weight prep
    prep_all_kernel<<<dim3(335), 256, 0, stream>>>(
        cv0_off_w, c0_off_w, cvs_off_w, cs_off_w, cv0_w, c0_w, cvs_w, cs_w);

    // 2: x -> NHWC fp32 + bf16 hi/lo (both branches)
    split_x_kernel<<<dim3(4, 256), 256, 0, stream>>>(x);

    // 3-4: stage-1 offset convs (MFMA)
    mfma_conv_kernel<3, 1, 1, 2, 1><<<dim3(128, 2), 256, 0, stream>>>(
        XA_HI, XA_LO, AW_A1, cv0_off_b, OFF_A, 18);
    mfma_conv_kernel<5, 1, 2, 4, 1><<<dim3(128, 4), 256, 0, stream>>>(
        XB_HI, XB_LO, AW_B1, c0_off_b, OFF_B, 50);

    // 5: stage-1 bilinear precompute (both branches)
    precomp_kernel<3, 5><<<dim3(1088), 256, 0, stream>>>(
        OFF_A, PRE_S1_A, 1, 1, OFF_B, PRE_S1_B, 2, 1, 288);

    // 6: stage-1 sampling (+ hi/lo emit)
    sample_kernel<9, 25, 1><<<dim3(4096), 256, 0, stream>>>(
        XA_F32, PRE_S1_A, DW_A1, A1_F32, A1_HI, A1_LO,
        XB_F32, PRE_S1_B, DW_B1, B1_F32, B1_HI, B1_LO);

    // 7-8: stage-2 offset convs (MFMA)
    mfma_conv_kernel<5, 3, 6, 4, 1><<<dim3(128, 4), 256, 0, stream>>>(
        A1_HI, A1_LO, AW_A2, cvs_off_b, OFF_A, 50);
    mfma_conv_kernel<7, 3, 9, 8, 2><<<dim3(128, 4), 256, 0, stream>>>(
        B1_HI, B1_LO, AW_B2, cs_off_b, OFF_B, 98);

    // 9: stage-2 bilinear precompute
    precomp_kernel<5, 7><<<dim3(2368), 256, 0, stream>>>(
        OFF_A, PRE_S2_A, 6, 3, OFF_B, PRE_S2_B, 9, 3, 800);

    // 10: stage-2 sampling
    sample_kernel<25, 49, 0><<<dim3(4096), 256, 0, stream>>>(
        A1_F32, PRE_S2_A, DW_A2, A2_F32, 0, 0,
        B1_F32, PRE_S2_B, DW_B2, B2_F32, 0, 0);

    // 11: 1x1 convs + gating multiply
    final_kernel<<<dim3(64, 4, 2), 256, 0, stream>>>(
        x, A2_F32, B2_F32, conv1_w, conv1_b, conv2_w, conv2_b, out);
}

// Round 10
// 200.569 us; speedup vs baseline: 1.8497x; 1.0902x over previous
//
#include <hip/hip_runtime.h>
#include <hip/hip_bf16.h>

#define HW   4096

typedef __bf16 bf_t;
typedef __bf16 bf8_t __attribute__((ext_vector_type(8)));
typedef float  f4_t  __attribute__((ext_vector_type(4)));
typedef int    i4_t  __attribute__((ext_vector_type(4)));

// Static device workspace (element offsets into g_ws, in floats):
#define OFF_A    0              // 2*50*HW NCHW offset maps
#define OFF_B    409600         // 2*98*HW
#define A1_F32   1212416        // NHWC fp32 [b][4096][64] = 524288 each
#define B1_F32   1736704
#define A2_F32   2260992
#define B2_F32   2785280
#define XA_F32   3309568
#define XB_F32   3833856
#define XA_HI    4358144        // bf16 NHWC = 262144 floats each
#define XA_LO    4620288
#define XB_HI    4882432
#define XB_LO    5144576
#define A1_HI    5406720
#define A1_LO    5668864
#define B1_HI    5931008
#define B1_LO    6193152
#define AW_A1    6455296        // conv weight packs (bf16 A-frag)
#define AW_B1    6464512
#define AW_A2    6515712
#define AW_B2    6566912
#define DW_A1    6767616        // depthwise weights transposed [KK][64]
#define DW_B1    6768192
#define DW_A2    6769792
#define DW_B2    6771392
#define WS_TOT   6774528

__device__ __align__(16) float g_ws[WS_TOT];

__device__ __forceinline__ bf8_t bf8_zero() {
    bf8_t v;
#pragma unroll
    for (int j = 0; j < 8; ++j) v[j] = (bf_t)0.f;
    return v;
}

// ---------------------------------------------------------------------------
// Weight prep helpers (range-dispatched).
// ---------------------------------------------------------------------------
__device__ __forceinline__ void prep_wA_dev(const float* wg, int aw_off,
                                            int Cout, int K, int NCOT, int lb) {
    const int KK = K * K;
    const int total = KK * NCOT * 128;
    const int idx = lb * 256 + threadIdx.x;
    if (idx >= total) return;
    bf_t* aw = (bf_t*)(g_ws + aw_off);
    int lane = idx & 63;
    int kh   = (idx >> 6) & 1;
    int cot  = (idx >> 7) % NCOT;
    int tap  = idx / (128 * NCOT);
    int co   = cot * 16 + (lane & 15);
    int ci0  = kh * 32 + (lane >> 4) * 8;
    bf8_t v;
#pragma unroll
    for (int j = 0; j < 8; ++j) {
        float f = (co < Cout) ? wg[(co * 64 + ci0 + j) * KK + tap] : 0.f;
        v[j] = (bf_t)f;
    }
    *(bf8_t*)&aw[(long)idx * 8] = v;
}

__device__ __forceinline__ void prep_dwT_dev(const float* w, int dst_off,
                                             int KK, int lb) {
    const int idx = lb * 256 + threadIdx.x;
    if (idx < KK * 64) {
        int c = idx & 63, kk = idx >> 6;
        g_ws[dst_off + kk * 64 + c] = w[c * KK + kk];
    }
}

// ---------------------------------------------------------------------------
// Kernel 1: all weight prep (blocks 0..334) + x -> NHWC fp32 / bf16 hi-lo
// split (blocks 335..1358). Independent work, one launch.
// ---------------------------------------------------------------------------
__global__ __launch_bounds__(256) void prep_split_kernel(
    const float* __restrict__ x,
    const float* cv0_off_w, const float* c0_off_w,
    const float* cvs_off_w, const float* cs_off_w,
    const float* cv0_w, const float* c0_w,
    const float* cvs_w, const float* cs_w)
{
    __shared__ float lds[16 * 68];
    const int bi = blockIdx.x;
    if (bi < 335) {
        if      (bi < 9)   prep_wA_dev(cv0_off_w, AW_A1, 18, 3, 2, bi);
        else if (bi < 59)  prep_wA_dev(c0_off_w,  AW_B1, 50, 5, 4, bi - 9);
        else if (bi < 109) prep_wA_dev(cvs_off_w, AW_A2, 50, 5, 4, bi - 59);
        else if (bi < 305) prep_wA_dev(cs_off_w,  AW_B2, 98, 7, 8, bi - 109);
        else if (bi < 308) prep_dwT_dev(cv0_w, DW_A1, 9,  bi - 305);
        else if (bi < 315) prep_dwT_dev(c0_w,  DW_B1, 25, bi - 308);
        else if (bi < 322) prep_dwT_dev(cvs_w, DW_A2, 25, bi - 315);
        else               prep_dwT_dev(cs_w,  DW_B2, 49, bi - 322);
        return;
    }
    const int s  = bi - 335;
    const int b  = s & 1;
    const int br = (s >> 1) & 1;
    const int p0 = (s >> 2) * 16;
    const float* sb = x + (long)b * (128 * HW) + (long)br * (64 * HW);
    bf_t*  dhi = (bf_t*)(g_ws + (br ? XB_HI : XA_HI));
    bf_t*  dlo = (bf_t*)(g_ws + (br ? XB_LO : XA_LO));
    float* df  = g_ws + (br ? XB_F32 : XA_F32);
    const int t = threadIdx.x;
    {
        const int px = t & 15;
        const int c0 = t >> 4;
#pragma unroll
        for (int pass = 0; pass < 4; ++pass) {
            int ci = c0 + pass * 16;
            lds[px * 68 + ci] = sb[ci * HW + p0 + px];
        }
    }
    __syncthreads();
    if (t < 128) {
        int px = t >> 3, q = t & 7;
        bf8_t vh, vl;
        f4_t  f0, f1;
#pragma unroll
        for (int j = 0; j < 8; ++j) {
            float a = lds[px * 68 + q * 8 + j];
            bf_t hcast = (bf_t)a;
            vh[j] = hcast;
            vl[j] = (bf_t)(a - (float)hcast);
            if (j < 4) f0[j] = a; else f1[j - 4] = a;
        }
        long base = (((long)b * 4096 + p0 + px) * 64) + q * 8;
        *(bf8_t*)&dhi[base] = vh;
        *(bf8_t*)&dlo[base] = vl;
        *(f4_t*)&df[base]     = f0;
        *(f4_t*)&df[base + 4] = f1;
    }
}

// ---------------------------------------------------------------------------
// MFMA implicit-GEMM conv body (hi/lo split input), dynamic-LDS version.
// ---------------------------------------------------------------------------
template<int K, int DIL, int PAD, int NCOT, int CPG>
__device__ __forceinline__ void mfma_conv_dev(
    int bx, int by, bf_t* smem,
    int hi_off, int lo_off, int aw_off, const float* __restrict__ bias,
    int dst_off, int Cout)
{
    constexpr int COLS = 64 + 2 * PAD;
    const bf_t* shi = (const bf_t*)(g_ws + hi_off);
    const bf_t* slo = (const bf_t*)(g_ws + lo_off);
    const bf_t* aw  = (const bf_t*)(g_ws + aw_off);
    float* dst = g_ws + dst_off;
    bf_t* lds0 = smem;
    bf_t* lds1 = smem + COLS * 72;

    const int t    = threadIdx.x;
    const int lane = t & 63;
    const int wv   = t >> 6;
    const int b    = bx >> 6;
    const int h    = bx & 63;
    const int ct0  = by * CPG;

    const int n0 = lane & 15;
    const int kq = lane >> 4;

    f4_t acc[CPG];
#pragma unroll
    for (int i = 0; i < CPG; ++i) acc[i] = (f4_t){0.f, 0.f, 0.f, 0.f};

    for (int ky = 0; ky < K; ++ky) {
        const int ih = h - PAD + ky * DIL;
        __syncthreads();
        if ((unsigned)ih < 64u) {
            const long rowb = ((long)b * 4096 + ih * 64) * 64;
            for (int c = t; c < COLS * 8; c += 256) {
                int col = c >> 3, q = c & 7;
                int iw = col - PAD;
                bf8_t vh, vl;
                if ((unsigned)iw < 64u) {
                    vh = *(const bf8_t*)&shi[rowb + iw * 64 + q * 8];
                    vl = *(const bf8_t*)&slo[rowb + iw * 64 + q * 8];
                } else { vh = bf8_zero(); vl = bf8_zero(); }
                *(bf8_t*)&lds0[col * 72 + q * 8] = vh;
                *(bf8_t*)&lds1[col * 72 + q * 8] = vl;
            }
        } else {
            bf8_t z = bf8_zero();
            for (int c = t; c < COLS * 8; c += 256) {
                int col = c >> 3, q = c & 7;
                *(bf8_t*)&lds0[col * 72 + q * 8] = z;
                *(bf8_t*)&lds1[col * 72 + q * 8] = z;
            }
        }
        __syncthreads();
#pragma unroll
        for (int kx = 0; kx < K; ++kx) {
            const int tap = ky * K + kx;
            bf8_t afr[CPG][2];
#pragma unroll
            for (int ct = 0; ct < CPG; ++ct)
#pragma unroll
                for (int kh = 0; kh < 2; ++kh)
                    afr[ct][kh] = *(const bf8_t*)
                        &aw[((((long)tap * NCOT + ct0 + ct) * 2 + kh) * 64 + lane) * 8];
            const int colb = (wv * 16 + n0 + kx * DIL) * 72;
#pragma unroll
            for (int kh = 0; kh < 2; ++kh) {
                const bf8_t bh = *(const bf8_t*)&lds0[colb + kh * 32 + kq * 8];
                const bf8_t bl = *(const bf8_t*)&lds1[colb + kh * 32 + kq * 8];
#pragma unroll
                for (int ct = 0; ct < CPG; ++ct) {
                    acc[ct] = __builtin_amdgcn_mfma_f32_16x16x32_bf16(
                        afr[ct][kh], bh, acc[ct], 0, 0, 0);
                    acc[ct] = __builtin_amdgcn_mfma_f32_16x16x32_bf16(
                        afr[ct][kh], bl, acc[ct], 0, 0, 0);
                }
            }
        }
    }

    const int w = wv * 16 + n0;
#pragma unroll
    for (int ct = 0; ct < CPG; ++ct) {
#pragma unroll
        for (int r = 0; r < 4; ++r) {
            int co = (ct0 + ct) * 16 + kq * 4 + r;
            if (co < Cout)
                dst[((long)b * Cout + co) * HW + h * 64 + w] = acc[ct][r] + bias[co];
        }
    }
}

// Kernel 2: stage-1 convs (k3: blocks 0..255, k5: 256..767). smem 19584 B.
__global__ __launch_bounds__(256) void conv_s1_kernel(
    const float* __restrict__ biasA, const float* __restrict__ biasB)
{
    extern __shared__ __align__(16) bf_t smem1[];
    const int bi = blockIdx.x;
    if (bi < 256)
        mfma_conv_dev<3, 1, 1, 2, 1>(bi & 127, bi >> 7, smem1,
                                     XA_HI, XA_LO, AW_A1, biasA, OFF_A, 18);
    else {
        const int s = bi - 256;
        mfma_conv_dev<5, 1, 2, 4, 1>(s & 127, s >> 7, smem1,
                                     XB_HI, XB_LO, AW_B1, biasB, OFF_B, 50);
    }
}

// Kernel 4: stage-2 convs (k5: 0..511, k7: 512..1023). smem 23616 B.
__global__ __launch_bounds__(256) void conv_s2_kernel(
    const float* __restrict__ biasA, const float* __restrict__ biasB)
{
    extern __shared__ __align__(16) bf_t smem2[];
    const int bi = blockIdx.x;
    if (bi < 512)
        mfma_conv_dev<5, 3, 6, 4, 1>(bi & 127, bi >> 7, smem2,
                                     A1_HI, A1_LO, AW_A2, biasA, OFF_A, 50);
    else {
        const int s = bi - 512;
        mfma_conv_dev<7, 3, 9, 8, 2>(s & 127, s >> 7, smem2,
                                     B1_HI, B1_LO, AW_B2, biasB, OFF_B, 98);
    }
}

// ---------------------------------------------------------------------------
// Fused deformable sampler: phase A computes this block's 4*KK bilinear
// records (weights + clamped corner byte-offsets) into LDS with lane-parallel
// coalesced work; phase B (lane = channel, wave = pixel) consumes them as
// wave-uniform LDS broadcasts + 4 coalesced corner gathers per tap.
// Identical arithmetic to the previous two-kernel pipeline.
// ---------------------------------------------------------------------------
template<int KK, int WRITE_HILO>
__device__ __forceinline__ void sample_fused_dev(
    int bx, float* recs, int src_off, int off_off, int dwt_off,
    int dst_off, int hi_off, int lo_off, int K, int pad, int dil)
{
    const int t   = threadIdx.x;
    const int pgi = ((bx & 7) << 8) | (bx >> 3);   // XCD-contiguous chunks

    // phase A: records for this block's 4 pixels
    for (int rec = t; rec < 4 * KK; rec += 256) {
        const int wv = rec & 3;
        const int kk = rec >> 2;
        const int pg = pgi * 4 + wv;
        const int b  = pg >> 12;
        const int p  = pg & 4095;
        const int h  = p >> 6, w = p & 63;
        const float oy = g_ws[off_off + ((long)(b * 2 * KK + 2 * kk)) * HW + p];
        const float ox = g_ws[off_off + ((long)(b * 2 * KK + 2 * kk + 1)) * HW + p];
        const float py = oy + (float)(h - pad + (kk / K) * dil);
        const float px = ox + (float)(w - pad + (kk % K) * dil);
        const float fy = floorf(py), fx = floorf(px);
        const float ly = py - fy,    lx = px - fx;
        const int y0 = (int)fy, x0 = (int)fx;
        const int y1 = y0 + 1,  x1 = x0 + 1;
        const float vy0 = ((unsigned)y0 < 64u) ? 1.f : 0.f;
        const float vy1 = ((unsigned)y1 < 64u) ? 1.f : 0.f;
        const float vx0 = ((unsigned)x0 < 64u) ? 1.f : 0.f;
        const float vx1 = ((unsigned)x1 < 64u) ? 1.f : 0.f;
        const float w00 = (1.f - ly) * (1.f - lx) * vy0 * vx0;
        const float w01 = (1.f - ly) * lx         * vy0 * vx1;
        const float w10 = ly         * (1.f - lx) * vy1 * vx0;
        const float w11 = ly         * lx         * vy1 * vx1;
        const int y0c = min(max(y0, 0), 63), y1c = min(max(y1, 0), 63);
        const int x0c = min(max(x0, 0), 63), x1c = min(max(x1, 0), 63);
        const int i00 = (y0c * 64 + x0c) * 256, i01 = (y0c * 64 + x1c) * 256;
        const int i10 = (y1c * 64 + x0c) * 256, i11 = (y1c * 64 + x1c) * 256;
        float* rp = &recs[rec * 8];
        *(f4_t*)rp       = (f4_t){w00, w01, w10, w11};
        *(i4_t*)(rp + 4) = (i4_t){i00, i01, i10, i11};
    }
    __syncthreads();

    // phase B
    const int c  = t & 63;
    const int wv = t >> 6;
    const int pg = pgi * 4 + wv;
    const int b  = pg >> 12;
    const int p  = pg & 4095;

    const char* sb = (const char*)(g_ws + src_off + ((long)b << 18)) + (c << 2);
    const float* wtp = g_ws + dwt_off + c;

    float acc = 0.f;
#pragma unroll 8
    for (int kk = 0; kk < KK; ++kk) {
        const float* rp = &recs[(kk * 4 + wv) * 8];
        const f4_t wq = *(const f4_t*)rp;
        const i4_t iq = *(const i4_t*)(rp + 4);
        const float v00 = *(const float*)(sb + iq.x);
        const float v01 = *(const float*)(sb + iq.y);
        const float v10 = *(const float*)(sb + iq.z);
        const float v11 = *(const float*)(sb + iq.w);
        const float val = wq.x * v00 + wq.y * v01 + wq.z * v10 + wq.w * v11;
        acc = fmaf(wtp[kk * 64], val, acc);
    }

    const long ob = ((long)b * 4096 + p) * 64 + c;
    g_ws[dst_off + ob] = acc;
    if (WRITE_HILO) {
        bf_t h16 = (bf_t)acc;
        ((bf_t*)(g_ws + hi_off))[ob] = h16;
        ((bf_t*)(g_ws + lo_off))[ob] = (bf_t)(acc - (float)h16);
    }
}

template<int KA, int KB, int WRITE_HILO>
__global__ __launch_bounds__(256) void sample_kernel(
    int srcA, int offA, int dwtA, int dstA, int hiA, int loA, int padA, int dilA,
    int srcB, int offB, int dwtB, int dstB, int hiB, int loB, int padB, int dilB)
{
    __shared__ __align__(16) float recs[4 * 49 * 8];
    const int bx = blockIdx.x;
    if (bx < 2048)
        sample_fused_dev<KA * KA, WRITE_HILO>(bx, recs, srcA, offA, dwtA,
                                              dstA, hiA, loA, KA, padA, dilA);
    else
        sample_fused_dev<KB * KB, WRITE_HILO>(bx - 2048, recs, srcB, offB, dwtB,
                                              dstB, hiB, loB, KB, padB, dilB);
}

// ---------------------------------------------------------------------------
// Kernel 6: per-branch 1x1 conv (+bias), then out = x * result.
// ---------------------------------------------------------------------------
__global__ __launch_bounds__(256) void final_kernel(
    const float* __restrict__ x,
    int aA_off, int aB_off,
    const float* __restrict__ w1, const float* __restrict__ b1,
    const float* __restrict__ w2, const float* __restrict__ b2,
    float* __restrict__ out)
{
    __shared__ float atile[64 * 65];
    __shared__ float wlds[64 * 32];
    const int t  = threadIdx.x;
    const int p0 = blockIdx.x * 64;
    const int by = blockIdx.y;
    const int b  = blockIdx.z;
    const bool brB  = (by >> 1) != 0;
    const int  cbase = (by & 1) * 32;
    const float* a  = g_ws + (brB ? aB_off : aA_off) + (long)b * (4096 * 64);
    const float* wg = brB ? w2 : w1;
    const float* bg = brB ? b2 : b1;

    {
        const int ci = t & 63;
        const int pxg = (t >> 6) * 16;
#pragma unroll
        for (int i = 0; i < 16; ++i) {
            int px = pxg + i;
            atile[px * 65 + ci] = a[(long)(p0 + px) * 64 + ci];
        }
    }
    for (int e = t; e < 2048; e += 256) {
        int col = e & 31, ci = e >> 5;
        wlds[ci * 32 + col] = wg[(cbase + col) * 64 + ci];
    }
    __syncthreads();

    const int px  = t & 63;
    const int cog = t >> 6;
    float acc[8] = {0, 0, 0, 0, 0, 0, 0, 0};
    for (int ci = 0; ci < 64; ++ci) {
        const float av = atile[px * 65 + ci];
        const float* wr = &wlds[ci * 32 + cog * 8];
#pragma unroll
        for (int j = 0; j < 8; ++j) acc[j] = fmaf(av, wr[j], acc[j]);
    }

    const int p = p0 + px;
#pragma unroll
    for (int j = 0; j < 8; ++j) {
        const int co = cbase + cog * 8 + j;
        const int cg = (brB ? 64 : 0) + co;
        const long o = ((long)b * 128 + cg) * HW + p;
        out[o] = (acc[j] + bg[co]) * x[o];
    }
}

// ---------------------------------------------------------------------------
extern "C" void kernel_launch(void* const* d_in, const int* in_sizes, int n_in,
                              void* d_out, int out_size, void* d_ws, size_t ws_size,
                              hipStream_t stream) {
    const float* x         = (const float*)d_in[0];
    const float* cv0_off_w = (const float*)d_in[1];
    const float* cv0_off_b = (const float*)d_in[2];
    const float* cv0_w     = (const float*)d_in[3];
    const float* cvs_off_w = (const float*)d_in[4];
    const float* cvs_off_b = (const float*)d_in[5];
    const float* cvs_w     = (const float*)d_in[6];
    const float* c0_off_w  = (const float*)d_in[7];
    const float* c0_off_b  = (const float*)d_in[8];
    const float* c0_w      = (const float*)d_in[9];
    const float* cs_off_w  = (const float*)d_in[10];
    const float* cs_off_b  = (const float*)d_in[11];
    const float* cs_w      = (const float*)d_in[12];
    const float* conv1_w   = (const float*)d_in[13];
    const float* conv1_b   = (const float*)d_in[14];
    const float* conv2_w   = (const float*)d_in[15];
    const float* conv2_b   = (const float*)d_in[16];
    float* out = (float*)d_out;
    (void)d_ws; (void)ws_size;

    // 1: weight prep + x NHWC/hi-lo split
    prep_split_kernel<<<dim3(1359), 256, 0, stream>>>(
        x, cv0_off_w, c0_off_w, cvs_off_w, cs_off_w, cv0_w, c0_w, cvs_w, cs_w);

    // 2: stage-1 offset convs (k3 + k5)
    conv_s1_kernel<<<dim3(768), 256, 19584, stream>>>(cv0_off_b, c0_off_b);

    // 3: stage-1 fused precompute+sampling (+ hi/lo emit)
    sample_kernel<3, 5, 1><<<dim3(4096), 256, 0, stream>>>(
        XA_F32, OFF_A, DW_A1, A1_F32, A1_HI, A1_LO, 1, 1,
        XB_F32, OFF_B, DW_B1, B1_F32, B1_HI, B1_LO, 2, 1);

    // 4: stage-2 offset convs (k5 + k7)
    conv_s2_kernel<<<dim3(1024), 256, 23616, stream>>>(cvs_off_b, cs_off_b);

    // 5: stage-2 fused precompute+sampling
    sample_kernel<5, 7, 0><<<dim3(4096), 256, 0, stream>>>(
        A1_F32, OFF_A, DW_A2, A2_F32, 0, 0, 6, 3,
        B1_F32, OFF_B, DW_B2, B2_F32, 0, 0, 9, 3);

    // 6: 1x1 convs + gating multiply
    final_kernel<<<dim3(64, 4, 2), 256, 0, stream>>>(
        x, A2_F32, B2_F32, conv1_w, conv1_b, conv2_w, conv2_b, out);
}

// Round 11
// 200.389 us; speedup vs baseline: 1.8513x; 1.0009x over previous
//
#include <hip/hip_runtime.h>
#include <hip/hip_bf16.h>

#define HW   4096

typedef __bf16 bf_t;
typedef __bf16 bf8_t __attribute__((ext_vector_type(8)));
typedef float  f4_t  __attribute__((ext_vector_type(4)));
typedef int    i4_t  __attribute__((ext_vector_type(4)));

// Static device workspace (element offsets into g_ws, in floats):
#define OFF_A    0              // 2*50*HW NCHW offset maps
#define OFF_B    409600         // 2*98*HW
#define A1_F32   1212416        // NHWC fp32 [b][4096][64] = 524288 each
#define B1_F32   1736704
#define A2_F32   2260992
#define B2_F32   2785280
#define XA_F32   3309568
#define XB_F32   3833856
#define XA_HI    4358144        // bf16 NHWC = 262144 floats each
#define XA_LO    4620288
#define XB_HI    4882432
#define XB_LO    5144576
#define A1_HI    5406720
#define A1_LO    5668864
#define B1_HI    5931008
#define B1_LO    6193152
#define AW_A1    6455296        // conv weight packs (bf16 A-frag)
#define AW_B1    6464512
#define AW_A2    6515712
#define AW_B2    6566912
#define DW_A1    6767616        // depthwise weights transposed [KK][64]
#define DW_B1    6768192
#define DW_A2    6769792
#define DW_B2    6771392
#define WS_TOT   6774528

__device__ __align__(16) float g_ws[WS_TOT];

__device__ __forceinline__ bf8_t bf8_zero() {
    bf8_t v;
#pragma unroll
    for (int j = 0; j < 8; ++j) v[j] = (bf_t)0.f;
    return v;
}

// ---------------------------------------------------------------------------
// Weight prep helpers (range-dispatched).
// ---------------------------------------------------------------------------
__device__ __forceinline__ void prep_wA_dev(const float* wg, int aw_off,
                                            int Cout, int K, int NCOT, int lb) {
    const int KK = K * K;
    const int total = KK * NCOT * 128;
    const int idx = lb * 256 + threadIdx.x;
    if (idx >= total) return;
    bf_t* aw = (bf_t*)(g_ws + aw_off);
    int lane = idx & 63;
    int kh   = (idx >> 6) & 1;
    int cot  = (idx >> 7) % NCOT;
    int tap  = idx / (128 * NCOT);
    int co   = cot * 16 + (lane & 15);
    int ci0  = kh * 32 + (lane >> 4) * 8;
    bf8_t v;
#pragma unroll
    for (int j = 0; j < 8; ++j) {
        float f = (co < Cout) ? wg[(co * 64 + ci0 + j) * KK + tap] : 0.f;
        v[j] = (bf_t)f;
    }
    *(bf8_t*)&aw[(long)idx * 8] = v;
}

__device__ __forceinline__ void prep_dwT_dev(const float* w, int dst_off,
                                             int KK, int lb) {
    const int idx = lb * 256 + threadIdx.x;
    if (idx < KK * 64) {
        int c = idx & 63, kk = idx >> 6;
        g_ws[dst_off + kk * 64 + c] = w[c * KK + kk];
    }
}

// ---------------------------------------------------------------------------
// Kernel 1: all weight prep (blocks 0..334) + x -> NHWC fp32 / bf16 hi-lo
// split (blocks 335..1358).
// ---------------------------------------------------------------------------
__global__ __launch_bounds__(256) void prep_split_kernel(
    const float* __restrict__ x,
    const float* cv0_off_w, const float* c0_off_w,
    const float* cvs_off_w, const float* cs_off_w,
    const float* cv0_w, const float* c0_w,
    const float* cvs_w, const float* cs_w)
{
    __shared__ float lds[16 * 68];
    const int bi = blockIdx.x;
    if (bi < 335) {
        if      (bi < 9)   prep_wA_dev(cv0_off_w, AW_A1, 18, 3, 2, bi);
        else if (bi < 59)  prep_wA_dev(c0_off_w,  AW_B1, 50, 5, 4, bi - 9);
        else if (bi < 109) prep_wA_dev(cvs_off_w, AW_A2, 50, 5, 4, bi - 59);
        else if (bi < 305) prep_wA_dev(cs_off_w,  AW_B2, 98, 7, 8, bi - 109);
        else if (bi < 308) prep_dwT_dev(cv0_w, DW_A1, 9,  bi - 305);
        else if (bi < 315) prep_dwT_dev(c0_w,  DW_B1, 25, bi - 308);
        else if (bi < 322) prep_dwT_dev(cvs_w, DW_A2, 25, bi - 315);
        else               prep_dwT_dev(cs_w,  DW_B2, 49, bi - 322);
        return;
    }
    const int s  = bi - 335;
    const int b  = s & 1;
    const int br = (s >> 1) & 1;
    const int p0 = (s >> 2) * 16;
    const float* sb = x + (long)b * (128 * HW) + (long)br * (64 * HW);
    bf_t*  dhi = (bf_t*)(g_ws + (br ? XB_HI : XA_HI));
    bf_t*  dlo = (bf_t*)(g_ws + (br ? XB_LO : XA_LO));
    float* df  = g_ws + (br ? XB_F32 : XA_F32);
    const int t = threadIdx.x;
    {
        const int px = t & 15;
        const int c0 = t >> 4;
#pragma unroll
        for (int pass = 0; pass < 4; ++pass) {
            int ci = c0 + pass * 16;
            lds[px * 68 + ci] = sb[ci * HW + p0 + px];
        }
    }
    __syncthreads();
    if (t < 128) {
        int px = t >> 3, q = t & 7;
        bf8_t vh, vl;
        f4_t  f0, f1;
#pragma unroll
        for (int j = 0; j < 8; ++j) {
            float a = lds[px * 68 + q * 8 + j];
            bf_t hcast = (bf_t)a;
            vh[j] = hcast;
            vl[j] = (bf_t)(a - (float)hcast);
            if (j < 4) f0[j] = a; else f1[j - 4] = a;
        }
        long base = (((long)b * 4096 + p0 + px) * 64) + q * 8;
        *(bf8_t*)&dhi[base] = vh;
        *(bf8_t*)&dlo[base] = vl;
        *(f4_t*)&df[base]     = f0;
        *(f4_t*)&df[base + 4] = f1;
    }
}

// ---------------------------------------------------------------------------
// MFMA implicit-GEMM conv body (hi/lo split input), dynamic-LDS version.
// ---------------------------------------------------------------------------
template<int K, int DIL, int PAD, int NCOT, int CPG>
__device__ __forceinline__ void mfma_conv_dev(
    int bx, int by, bf_t* smem,
    int hi_off, int lo_off, int aw_off, const float* __restrict__ bias,
    int dst_off, int Cout)
{
    constexpr int COLS = 64 + 2 * PAD;
    const bf_t* shi = (const bf_t*)(g_ws + hi_off);
    const bf_t* slo = (const bf_t*)(g_ws + lo_off);
    const bf_t* aw  = (const bf_t*)(g_ws + aw_off);
    float* dst = g_ws + dst_off;
    bf_t* lds0 = smem;
    bf_t* lds1 = smem + COLS * 72;

    const int t    = threadIdx.x;
    const int lane = t & 63;
    const int wv   = t >> 6;
    const int b    = bx >> 6;
    const int h    = bx & 63;
    const int ct0  = by * CPG;

    const int n0 = lane & 15;
    const int kq = lane >> 4;

    f4_t acc[CPG];
#pragma unroll
    for (int i = 0; i < CPG; ++i) acc[i] = (f4_t){0.f, 0.f, 0.f, 0.f};

    for (int ky = 0; ky < K; ++ky) {
        const int ih = h - PAD + ky * DIL;
        __syncthreads();
        if ((unsigned)ih < 64u) {
            const long rowb = ((long)b * 4096 + ih * 64) * 64;
            for (int c = t; c < COLS * 8; c += 256) {
                int col = c >> 3, q = c & 7;
                int iw = col - PAD;
                bf8_t vh, vl;
                if ((unsigned)iw < 64u) {
                    vh = *(const bf8_t*)&shi[rowb + iw * 64 + q * 8];
                    vl = *(const bf8_t*)&slo[rowb + iw * 64 + q * 8];
                } else { vh = bf8_zero(); vl = bf8_zero(); }
                *(bf8_t*)&lds0[col * 72 + q * 8] = vh;
                *(bf8_t*)&lds1[col * 72 + q * 8] = vl;
            }
        } else {
            bf8_t z = bf8_zero();
            for (int c = t; c < COLS * 8; c += 256) {
                int col = c >> 3, q = c & 7;
                *(bf8_t*)&lds0[col * 72 + q * 8] = z;
                *(bf8_t*)&lds1[col * 72 + q * 8] = z;
            }
        }
        __syncthreads();
#pragma unroll
        for (int kx = 0; kx < K; ++kx) {
            const int tap = ky * K + kx;
            bf8_t afr[CPG][2];
#pragma unroll
            for (int ct = 0; ct < CPG; ++ct)
#pragma unroll
                for (int kh = 0; kh < 2; ++kh)
                    afr[ct][kh] = *(const bf8_t*)
                        &aw[((((long)tap * NCOT + ct0 + ct) * 2 + kh) * 64 + lane) * 8];
            const int colb = (wv * 16 + n0 + kx * DIL) * 72;
#pragma unroll
            for (int kh = 0; kh < 2; ++kh) {
                const bf8_t bh = *(const bf8_t*)&lds0[colb + kh * 32 + kq * 8];
                const bf8_t bl = *(const bf8_t*)&lds1[colb + kh * 32 + kq * 8];
#pragma unroll
                for (int ct = 0; ct < CPG; ++ct) {
                    acc[ct] = __builtin_amdgcn_mfma_f32_16x16x32_bf16(
                        afr[ct][kh], bh, acc[ct], 0, 0, 0);
                    acc[ct] = __builtin_amdgcn_mfma_f32_16x16x32_bf16(
                        afr[ct][kh], bl, acc[ct], 0, 0, 0);
                }
            }
        }
    }

    const int w = wv * 16 + n0;
#pragma unroll
    for (int ct = 0; ct < CPG; ++ct) {
#pragma unroll
        for (int r = 0; r < 4; ++r) {
            int co = (ct0 + ct) * 16 + kq * 4 + r;
            if (co < Cout)
                dst[((long)b * Cout + co) * HW + h * 64 + w] = acc[ct][r] + bias[co];
        }
    }
}

// Kernel 2: stage-1 convs, k3 (256 blocks) / k5 (512 blocks) interleaved mod 3.
__global__ __launch_bounds__(256) void conv_s1_kernel(
    const float* __restrict__ biasA, const float* __restrict__ biasB)
{
    extern __shared__ __align__(16) bf_t smem1[];
    const int bi = blockIdx.x;
    const int g = bi / 3, r = bi % 3;
    if (r == 0)
        mfma_conv_dev<3, 1, 1, 2, 1>(g & 127, g >> 7, smem1,
                                     XA_HI, XA_LO, AW_A1, biasA, OFF_A, 18);
    else {
        const int s = 2 * g + (r - 1);
        mfma_conv_dev<5, 1, 2, 4, 1>(s & 127, s >> 7, smem1,
                                     XB_HI, XB_LO, AW_B1, biasB, OFF_B, 50);
    }
}

// Kernel 4: stage-2 convs, k5 / k7 interleaved even/odd. smem 23616 B.
__global__ __launch_bounds__(256) void conv_s2_kernel(
    const float* __restrict__ biasA, const float* __restrict__ biasB)
{
    extern __shared__ __align__(16) bf_t smem2[];
    const int bi = blockIdx.x;
    const int s = bi >> 1;
    if ((bi & 1) == 0)
        mfma_conv_dev<5, 3, 6, 4, 1>(s & 127, s >> 7, smem2,
                                     A1_HI, A1_LO, AW_A2, biasA, OFF_A, 50);
    else
        mfma_conv_dev<7, 3, 9, 8, 2>(s & 127, s >> 7, smem2,
                                     B1_HI, B1_LO, AW_B2, biasB, OFF_B, 98);
}

// ---------------------------------------------------------------------------
// Fused deformable sampler: phase A computes this block's 4*KK bilinear
// records into LDS; phase B (lane = channel, wave = pixel) consumes them as
// wave-uniform LDS broadcasts + coalesced corner gathers. Depthwise weights
// preloaded into registers; tap loop fully unrolled.
// ---------------------------------------------------------------------------
template<int KK, int WRITE_HILO>
__device__ __forceinline__ void sample_fused_dev(
    int bx, float* recs, int src_off, int off_off, int dwt_off,
    int dst_off, int hi_off, int lo_off, int K, int pad, int dil)
{
    const int t   = threadIdx.x;
    const int pgi = ((bx & 7) << 8) | (bx >> 3);   // XCD-contiguous chunks

    // phase A: records for this block's 4 pixels
    for (int rec = t; rec < 4 * KK; rec += 256) {
        const int wv = rec & 3;
        const int kk = rec >> 2;
        const int pg = pgi * 4 + wv;
        const int b  = pg >> 12;
        const int p  = pg & 4095;
        const int h  = p >> 6, w = p & 63;
        const float oy = g_ws[off_off + ((long)(b * 2 * KK + 2 * kk)) * HW + p];
        const float ox = g_ws[off_off + ((long)(b * 2 * KK + 2 * kk + 1)) * HW + p];
        const float py = oy + (float)(h - pad + (kk / K) * dil);
        const float px = ox + (float)(w - pad + (kk % K) * dil);
        const float fy = floorf(py), fx = floorf(px);
        const float ly = py - fy,    lx = px - fx;
        const int y0 = (int)fy, x0 = (int)fx;
        const int y1 = y0 + 1,  x1 = x0 + 1;
        const float vy0 = ((unsigned)y0 < 64u) ? 1.f : 0.f;
        const float vy1 = ((unsigned)y1 < 64u) ? 1.f : 0.f;
        const float vx0 = ((unsigned)x0 < 64u) ? 1.f : 0.f;
        const float vx1 = ((unsigned)x1 < 64u) ? 1.f : 0.f;
        const float w00 = (1.f - ly) * (1.f - lx) * vy0 * vx0;
        const float w01 = (1.f - ly) * lx         * vy0 * vx1;
        const float w10 = ly         * (1.f - lx) * vy1 * vx0;
        const float w11 = ly         * lx         * vy1 * vx1;
        const int y0c = min(max(y0, 0), 63), y1c = min(max(y1, 0), 63);
        const int x0c = min(max(x0, 0), 63), x1c = min(max(x1, 0), 63);
        const int i00 = (y0c * 64 + x0c) * 256, i01 = (y0c * 64 + x1c) * 256;
        const int i10 = (y1c * 64 + x0c) * 256, i11 = (y1c * 64 + x1c) * 256;
        float* rp = &recs[rec * 8];
        *(f4_t*)rp       = (f4_t){w00, w01, w10, w11};
        *(i4_t*)(rp + 4) = (i4_t){i00, i01, i10, i11};
    }

    // depthwise weight preload (registers), overlaps phase A latency
    const int c  = t & 63;
    float wreg[KK];
    {
        const float* wtp = g_ws + dwt_off + c;
#pragma unroll
        for (int kk = 0; kk < KK; ++kk) wreg[kk] = wtp[kk * 64];
    }
    __syncthreads();

    // phase B
    const int wv = t >> 6;
    const int pg = pgi * 4 + wv;
    const int b  = pg >> 12;
    const int p  = pg & 4095;

    const char* sb = (const char*)(g_ws + src_off + ((long)b << 18)) + (c << 2);

    float acc = 0.f;
#pragma unroll
    for (int kk = 0; kk < KK; ++kk) {
        const float* rp = &recs[(kk * 4 + wv) * 8];
        const f4_t wq = *(const f4_t*)rp;
        const i4_t iq = *(const i4_t*)(rp + 4);
        const float v00 = *(const float*)(sb + iq.x);
        const float v01 = *(const float*)(sb + iq.y);
        const float v10 = *(const float*)(sb + iq.z);
        const float v11 = *(const float*)(sb + iq.w);
        const float val = wq.x * v00 + wq.y * v01 + wq.z * v10 + wq.w * v11;
        acc = fmaf(wreg[kk], val, acc);
    }

    const long ob = ((long)b * 4096 + p) * 64 + c;
    g_ws[dst_off + ob] = acc;
    if (WRITE_HILO) {
        bf_t h16 = (bf_t)acc;
        ((bf_t*)(g_ws + hi_off))[ob] = h16;
        ((bf_t*)(g_ws + lo_off))[ob] = (bf_t)(acc - (float)h16);
    }
}

template<int KA, int KB, int WRITE_HILO>
__global__ __launch_bounds__(256) void sample_kernel(
    int srcA, int offA, int dwtA, int dstA, int hiA, int loA, int padA, int dilA,
    int srcB, int offB, int dwtB, int dstB, int hiB, int loB, int padB, int dilB)
{
    __shared__ __align__(16) float recs[4 * 49 * 8];
    const int bx = blockIdx.x;
    const int s = bx >> 1;
    if ((bx & 1) == 0)       // interleaved: flattens A/B duration imbalance
        sample_fused_dev<KA * KA, WRITE_HILO>(s, recs, srcA, offA, dwtA,
                                              dstA, hiA, loA, KA, padA, dilA);
    else
        sample_fused_dev<KB * KB, WRITE_HILO>(s, recs, srcB, offB, dwtB,
                                              dstB, hiB, loB, KB, padB, dilB);
}

// ---------------------------------------------------------------------------
// Kernel 6: per-branch 1x1 conv (+bias), then out = x * result.
// ---------------------------------------------------------------------------
__global__ __launch_bounds__(256) void final_kernel(
    const float* __restrict__ x,
    int aA_off, int aB_off,
    const float* __restrict__ w1, const float* __restrict__ b1,
    const float* __restrict__ w2, const float* __restrict__ b2,
    float* __restrict__ out)
{
    __shared__ float atile[64 * 65];
    __shared__ float wlds[64 * 32];
    const int t  = threadIdx.x;
    const int p0 = blockIdx.x * 64;
    const int by = blockIdx.y;
    const int b  = blockIdx.z;
    const bool brB  = (by >> 1) != 0;
    const int  cbase = (by & 1) * 32;
    const float* a  = g_ws + (brB ? aB_off : aA_off) + (long)b * (4096 * 64);
    const float* wg = brB ? w2 : w1;
    const float* bg = brB ? b2 : b1;

    {
        const int ci = t & 63;
        const int pxg = (t >> 6) * 16;
#pragma unroll
        for (int i = 0; i < 16; ++i) {
            int px = pxg + i;
            atile[px * 65 + ci] = a[(long)(p0 + px) * 64 + ci];
        }
    }
    for (int e = t; e < 2048; e += 256) {
        int col = e & 31, ci = e >> 5;
        wlds[ci * 32 + col] = wg[(cbase + col) * 64 + ci];
    }
    __syncthreads();

    const int px  = t & 63;
    const int cog = t >> 6;
    float acc[8] = {0, 0, 0, 0, 0, 0, 0, 0};
    for (int ci = 0; ci < 64; ++ci) {
        const float av = atile[px * 65 + ci];
        const float* wr = &wlds[ci * 32 + cog * 8];
#pragma unroll
        for (int j = 0; j < 8; ++j) acc[j] = fmaf(av, wr[j], acc[j]);
    }

    const int p = p0 + px;
#pragma unroll
    for (int j = 0; j < 8; ++j) {
        const int co = cbase + cog * 8 + j;
        const int cg = (brB ? 64 : 0) + co;
        const long o = ((long)b * 128 + cg) * HW + p;
        out[o] = (acc[j] + bg[co]) * x[o];
    }
}

// ---------------------------------------------------------------------------
extern "C" void kernel_launch(void* const* d_in, const int* in_sizes, int n_in,
                              void* d_out, int out_size, void* d_ws, size_t ws_size,
                              hipStream_t stream) {
    const float* x         = (const float*)d_in[0];
    const float* cv0_off_w = (const float*)d_in[1];
    const float* cv0_off_b = (const float*)d_in[2];
    const float* cv0_w     = (const float*)d_in[3];
    const float* cvs_off_w = (const float*)d_in[4];
    const float* cvs_off_b = (const float*)d_in[5];
    const float* cvs_w     = (const float*)d_in[6];
    const float* c0_off_w  = (const float*)d_in[7];
    const float* c0_off_b  = (const float*)d_in[8];
    const float* c0_w      = (const float*)d_in[9];
    const float* cs_off_w  = (const float*)d_in[10];
    const float* cs_off_b  = (const float*)d_in[11];
    const float* cs_w      = (const float*)d_in[12];
    const float* conv1_w   = (const float*)d_in[13];
    const float* conv1_b   = (const float*)d_in[14];
    const float* conv2_w   = (const float*)d_in[15];
    const float* conv2_b   = (const float*)d_in[16];
    float* out = (float*)d_out;
    (void)d_ws; (void)ws_size;

    // 1: weight prep + x NHWC/hi-lo split
    prep_split_kernel<<<dim3(1359), 256, 0, stream>>>(
        x, cv0_off_w, c0_off_w, cvs_off_w, cs_off_w, cv0_w, c0_w, cvs_w, cs_w);

    // 2: stage-1 offset convs (k3 + k5, interleaved)
    conv_s1_kernel<<<dim3(768), 256, 19584, stream>>>(cv0_off_b, c0_off_b);

    // 3: stage-1 fused precompute+sampling (+ hi/lo emit)
    sample_kernel<3, 5, 1><<<dim3(4096), 256, 0, stream>>>(
        XA_F32, OFF_A, DW_A1, A1_F32, A1_HI, A1_LO, 1, 1,
        XB_F32, OFF_B, DW_B1, B1_F32, B1_HI, B1_LO, 2, 1);

    // 4: stage-2 offset convs (k5 + k7, interleaved)
    conv_s2_kernel<<<dim3(1024), 256, 23616, stream>>>(cvs_off_b, cs_off_b);

    // 5: stage-2 fused precompute+sampling
    sample_kernel<5, 7, 0><<<dim3(4096), 256, 0, stream>>>(
        A1_F32, OFF_A, DW_A2, A2_F32, 0, 0, 6, 3,
        B1_F32, OFF_B, DW_B2, B2_F32, 0, 0, 9, 3);

    // 6: 1x1 convs + gating multiply
    final_kernel<<<dim3(64, 4, 2), 256, 0, stream>>>(
        x, A2_F32, B2_F32, conv1_w, conv1_b, conv2_w, conv2_b, out);
}